// Round 3
// baseline (729.705 us; speedup 1.0000x reference)
//
#include <hip/hip_runtime.h>
#include <hip/hip_bf16.h>
#include <hip/hip_fp16.h>

#define NN 131072
#define KK 27
#define CC 32
#define EPSV 1e-5f

// ---------------------------------------------------------------------------
// Tier-1 (partitioned gather) workspace layout (bytes):
//   [0,256)       f32 stats
//   [256,2304)    u32 gcnt[512]          (bin fill counters, memset 0)
//   [2304,59648)  u32 koff[512][28]      (per-bin per-tap CSR offsets)
//   [59648,...)   f16 wperm              (55296 B, MFMA B-fragment layout)
//   [WS_RAW]      u32 raw[512][7680]     (unsorted bin records)
//   [WS_SORT]     u32 sorted[512][7680]  (k-sorted bin records)
//   [WS_DATA16]   f16 data16[N][32]
#define NBINS   512
#define CAPBIN  7680          // bin capacity (mean 6912, sigma 83 -> +9.2 sigma)
#define CAPB    24            // per-bin LDS staging slots in partition
#define WS_STATS   0
#define WS_GCNT    256
#define WS_KOFF    2304
#define WS_WPERM   59648
#define WS_RAW     114944
#define WS_SORT    15843584
#define WS_DATA16  31572224
#define WS_NEED_GATHER ((size_t)WS_DATA16 + (size_t)NN * CC * 2)   // 39.96 MB

// Tier-2 (R1 atomic-scatter, proven 271us) layout
#define T2_WPERM 256
#define T2_ACC   65536
#define WS_NEED_T2 ((size_t)T2_ACC + (size_t)NN * CC * 2)

typedef __bf16 bf16x8 __attribute__((ext_vector_type(8)));
typedef _Float16 f16x8 __attribute__((ext_vector_type(8)));
typedef short s16x8 __attribute__((ext_vector_type(8)));
typedef float f32x4 __attribute__((ext_vector_type(4)));

__device__ inline unsigned short f2bf(float f) {
    unsigned int u = __float_as_uint(f);
    u += 0x7FFF + ((u >> 16) & 1);   // round-to-nearest-even
    return (unsigned short)(u >> 16);
}
__device__ inline unsigned short f2h(float f) {
    return __builtin_bit_cast(unsigned short, __float2half(f));
}

// ===========================================================================
// Tier-1 kernels
// ===========================================================================

// Fused prep (verified in R2): blocks [0,2048) convert data f32->f16;
// blocks [2048,2156) permute weights into f16 MFMA B-fragment layout.
// Logical out-channel c -> MFMA ch-half (c&1) at physical column (c>>1);
// fragment element (fl, j): fl = col | ((ci>>3)<<4), j = ci&7.
__global__ __launch_bounds__(256) void prep_kernel(
    const float* __restrict__ data, const float* __restrict__ weight,
    unsigned short* __restrict__ data16, unsigned short* __restrict__ wperm)
{
    const int b = blockIdx.x;
    if (b < 2048) {
        const int tg = b * 256 + threadIdx.x;          // 8 floats each
        const float4 v0 = ((const float4*)data)[tg * 2];
        const float4 v1 = ((const float4*)data)[tg * 2 + 1];
        union { unsigned short us[8]; uint4 u4; } o;
        o.us[0] = f2h(v0.x); o.us[1] = f2h(v0.y);
        o.us[2] = f2h(v0.z); o.us[3] = f2h(v0.w);
        o.us[4] = f2h(v1.x); o.us[5] = f2h(v1.y);
        o.us[6] = f2h(v1.z); o.us[7] = f2h(v1.w);
        ((uint4*)data16)[tg] = o.u4;
    } else {
        const int p = (b - 2048) * 256 + threadIdx.x;  // < 27648 exactly
        const int k  = p >> 10;
        const int ci = (p >> 5) & 31;
        const int c  = p & 31;
        const unsigned short v = f2h(weight[p]);
        const int chalf = c & 1;
        const int col   = c >> 1;
        const int fl = col | ((ci >> 3) << 4);
        const int j = ci & 7;
        wperm[(((k << 1) | chalf) * 64 + fl) * 8 + j] = v;
    }
}

// Partition 3.54M (i,k) pairs into 512 bins of 256 output rows, using LDS
// staging so global writes are bulk runs (L2 line-merged), not random 4B
// scatters (R2's fill_kernel paid 64B of HBM writeback per 4B record).
// Record: k(5b)<<25 | i(17b)<<8 | (o&255).
__global__ __launch_bounds__(256) void partition_kernel(
    const int* __restrict__ neigh, unsigned int* __restrict__ gcnt,
    unsigned int* __restrict__ raw)
{
    __shared__ unsigned int lcnt[NBINS];
    __shared__ unsigned int lbuf[NBINS * CAPB];   // 49152 B
    const int tid = threadIdx.x;
    for (int t = tid; t < NBINS; t += 256) lcnt[t] = 0;
    __syncthreads();
    const int base = blockIdx.x * 4096;
    #pragma unroll
    for (int j = 0; j < 16; ++j) {
        const int p = base + j * 256 + tid;
        const unsigned int o = (unsigned int)neigh[p];
        const unsigned int i = (unsigned int)p / 27u;
        const unsigned int k = (unsigned int)p - i * 27u;
        const unsigned int rec = (k << 25) | (i << 8) | (o & 255u);
        const unsigned int bin = o >> 8;
        const unsigned int slot = atomicAdd(&lcnt[bin], 1u);
        if (slot < CAPB) {
            lbuf[bin * CAPB + slot] = rec;
        } else {                                   // rare overflow: direct append
            const unsigned int gp = atomicAdd(&gcnt[bin], 1u);
            if (gp < CAPBIN) raw[(size_t)bin * CAPBIN + gp] = rec;
        }
    }
    __syncthreads();
    for (int b2 = tid; b2 < NBINS; b2 += 256) {
        unsigned int nb = lcnt[b2]; if (nb > CAPB) nb = CAPB;
        if (nb == 0) continue;
        const unsigned int gbase = atomicAdd(&gcnt[b2], nb);
        for (unsigned int s = 0; s < nb; ++s) {
            const unsigned int gp = gbase + s;
            if (gp < CAPBIN) raw[(size_t)b2 * CAPBIN + gp] = lbuf[b2 * CAPB + s];
        }
    }
}

// Per-bin counting sort by tap k (all traffic confined to one 30KB window,
// L2-local). Emits k-stripped records (i<<8|o_local) + 28 CSR offsets.
__global__ __launch_bounds__(256) void binsort_kernel(
    const unsigned int* __restrict__ gcnt, const unsigned int* __restrict__ raw,
    unsigned int* __restrict__ sorted, unsigned int* __restrict__ koff)
{
    __shared__ unsigned int hist[28];
    __shared__ unsigned int woffs[27];
    const int b = blockIdx.x, tid = threadIdx.x;
    if (tid < 28) hist[tid] = 0;
    __syncthreads();
    unsigned int n = gcnt[b]; if (n > CAPBIN) n = CAPBIN;
    const unsigned int* rp = raw + (size_t)b * CAPBIN;
    for (unsigned int t = tid; t < n; t += 256)
        atomicAdd(&hist[rp[t] >> 25], 1u);
    __syncthreads();
    if (tid == 0) {
        unsigned int run = 0;
        for (int j = 0; j < 27; ++j) {
            const unsigned int h = hist[j];
            hist[j] = run; woffs[j] = run; run += h;
        }
        hist[27] = run;
    }
    __syncthreads();
    if (tid < 28) koff[b * 28 + tid] = hist[tid];
    unsigned int* sp = sorted + (size_t)b * CAPBIN;
    for (unsigned int t = tid; t < n; t += 256) {
        const unsigned int r = rp[t];
        const unsigned int pos = atomicAdd(&woffs[r >> 25], 1u);
        sp[pos] = r & 0x01FFFFFFu;
    }
}

// Gather-GEMM per bin: LDS f32 accumulator (256 rows x stride 33), waves
// split taps (k = wv, wv+4, ...). Per wave-step: 16 records -> A-frag rows
// (gathered 64B data16 lines), shared B = wperm[k], one 16x16x32 f16 MFMA
// pair, then ds_add_f32 scatter of C rows into the accumulator.
// Records + data are 2-deep software-pipelined. Rows written once, stats fused.
__global__ __launch_bounds__(256) void gathermm_kernel(
    const unsigned short* __restrict__ data16,
    const unsigned short* __restrict__ wperm,
    const unsigned int* __restrict__ sorted,
    const unsigned int* __restrict__ koff,
    float* __restrict__ out, float* __restrict__ stats)
{
    __shared__ float accS[256 * 33];              // 33792 B
    __shared__ float ps[8][32], ps2[8][32];       // 2048 B
    const int tid = threadIdx.x;
    const int lane = tid & 63, wv = tid >> 6;
    const int b = blockIdx.x;

    for (int t = tid; t < 256 * 33; t += 256) accS[t] = 0.f;
    __syncthreads();

    const int q = lane >> 4, m = lane & 15;
    const uint4* wq = (const uint4*)wperm;
    const uint4* dq = (const uint4*)data16;
    const unsigned int* so = sorted + (size_t)b * CAPBIN;
    const unsigned int* kb = koff + b * 28;
    const f32x4 zero = {0.f, 0.f, 0.f, 0.f};

    for (int k = wv; k < KK; k += 4) {
        const int s0  = (int)kb[k];
        const int len = (int)kb[k + 1] - s0;
        if (len <= 0) continue;
        const unsigned int* sp2 = so + s0;
        const int last = len - 1;
        const uint4 b0 = wq[(k * 2) * 64 + lane];
        const uint4 b1 = wq[(k * 2 + 1) * 64 + lane];

        // pipeline prologue: rec/data for group 0, rec for group 1
        unsigned int recA = sp2[m < last ? m : last];
        uint4 avA = dq[((recA >> 8) << 2) | q];
        const int i1 = 16 + m;
        unsigned int recB = sp2[i1 < last ? i1 : last];

        for (int t = 0; t < len; t += 16) {
            // issue group t+32 record and group t+16 data (FIFO: waiting on
            // avA below does not drain these newer loads)
            const int i2 = t + 32 + m;
            const unsigned int recC = sp2[i2 < last ? i2 : last];
            const uint4 avB = dq[((recB >> 8) << 2) | q];

            const f32x4 d0 = __builtin_amdgcn_mfma_f32_16x16x32_f16(
                __builtin_bit_cast(f16x8, avA), __builtin_bit_cast(f16x8, b0),
                zero, 0, 0, 0);
            const f32x4 d1 = __builtin_amdgcn_mfma_f32_16x16x32_f16(
                __builtin_bit_cast(f16x8, avA), __builtin_bit_cast(f16x8, b1),
                zero, 0, 0, 0);
            // C row j = 4q+r holds record (t+4q+r); lane column m -> logical
            // channels 2m (d0), 2m+1 (d1). Scatter into LDS accumulator.
            #pragma unroll
            for (int r2 = 0; r2 < 4; ++r2) {
                const int jr = t + 4 * q + r2;
                if (jr < len) {
                    const unsigned int rr = sp2[jr];      // L1-hot line
                    const int o = (int)(rr & 255u);
                    atomicAdd(&accS[o * 33 + 2 * m],     d0[r2]);
                    atomicAdd(&accS[o * 33 + 2 * m + 1], d1[r2]);
                }
            }
            avA = avB; recB = recC;
        }
    }
    __syncthreads();

    // ---- write rows once (streaming) + fused BN stats ----
    {
        const int row = tid;                       // 256 rows, 256 threads
        const float* ar = &accS[row * 33];
        float4* op = (float4*)(out + ((size_t)(b * 256 + row)) * 32);
        #pragma unroll
        for (int c4 = 0; c4 < 8; ++c4) {
            float4 v;
            v.x = ar[c4 * 4]; v.y = ar[c4 * 4 + 1];
            v.z = ar[c4 * 4 + 2]; v.w = ar[c4 * 4 + 3];
            op[c4] = v;
        }
    }
    {
        const int cc = tid & 31, rg = tid >> 5;
        float s = 0.f, s2 = 0.f;
        for (int rr = rg; rr < 256; rr += 8) {
            const float v = accS[rr * 33 + cc];
            s += v; s2 += v * v;
        }
        ps[rg][cc] = s; ps2[rg][cc] = s2;
        __syncthreads();
        if (tid < 32) {
            float S = 0.f, S2 = 0.f;
            #pragma unroll
            for (int g = 0; g < 8; ++g) { S += ps[g][tid]; S2 += ps2[g][tid]; }
            atomicAdd(&stats[tid], S);
            atomicAdd(&stats[32 + tid], S2);
        }
    }
}

// BN+ReLU in place on f32 out (tier-1 and tier-3)
__global__ __launch_bounds__(256) void bn_relu_f32_kernel(
    float* __restrict__ out, const float* __restrict__ stats,
    const float* __restrict__ gamma, const float* __restrict__ beta)
{
    __shared__ float sc[32], sh[32];
    const int tid = threadIdx.x;
    if (tid < 32) {
        const float mean = stats[tid] * (1.0f / NN);
        const float var  = stats[32 + tid] * (1.0f / NN) - mean * mean;
        const float s = gamma[tid] * rsqrtf(var + EPSV);
        sc[tid] = s;
        sh[tid] = beta[tid] - mean * s;
    }
    __syncthreads();
    const int idx = blockIdx.x * 256 + tid;
    float4 v = ((float4*)out)[idx];
    const int cb = (idx & 7) << 2;
    v.x = fmaxf(v.x * sc[cb]     + sh[cb],     0.f);
    v.y = fmaxf(v.y * sc[cb + 1] + sh[cb + 1], 0.f);
    v.z = fmaxf(v.z * sc[cb + 2] + sh[cb + 2], 0.f);
    v.w = fmaxf(v.w * sc[cb + 3] + sh[cb + 3], 0.f);
    ((float4*)out)[idx] = v;
}

// ===========================================================================
// Tier-2: R1 atomic-scatter path (proven at 271 us)
// ===========================================================================
__global__ __launch_bounds__(256) void prep_weights_bf16_kernel(
    const float* __restrict__ weight, unsigned short* __restrict__ wperm)
{
    const int p = blockIdx.x * 256 + threadIdx.x;
    if (p >= KK * 1024) return;
    const int k  = p >> 10;
    const int ci = (p >> 5) & 31;
    const int c  = p & 31;
    const unsigned short v = f2bf(weight[p]);
    const int chalf = c & 1;
    const int col   = c >> 1;
    const int fl = col | ((ci >> 3) << 4);
    const int j = ci & 7;
    wperm[(((k << 1) | chalf) * 64 + fl) * 8 + j] = v;
}

__global__ __launch_bounds__(256) void scatter_kernel(
    const float* __restrict__ data, const unsigned short* __restrict__ wperm,
    const int* __restrict__ neigh, __half2* __restrict__ acc2)
{
    const int tid = threadIdx.x;
    const int lane = tid & 63;
    const int wv = tid >> 6;
    const int node_base = blockIdx.x * 128 + wv * 32;
    const int quad = lane >> 4;
    const int m = lane & 15;
    const int rq = quad << 2;

    s16x8 afr[2];
    #pragma unroll
    for (int g = 0; g < 2; ++g) {
        const int node = node_base + g * 16 + m;
        const float* src = data + node * 32 + quad * 8;
        const float4 v0 = *(const float4*)(src);
        const float4 v1 = *(const float4*)(src + 4);
        s16x8 s;
        s[0] = (short)f2bf(v0.x); s[1] = (short)f2bf(v0.y);
        s[2] = (short)f2bf(v0.z); s[3] = (short)f2bf(v0.w);
        s[4] = (short)f2bf(v1.x); s[5] = (short)f2bf(v1.y);
        s[6] = (short)f2bf(v1.z); s[7] = (short)f2bf(v1.w);
        afr[g] = s;
    }

    const s16x8* wp = (const s16x8*)wperm;
    const f32x4 zero = {0.f, 0.f, 0.f, 0.f};

    int nj0[4], nj1[4];
    #pragma unroll
    for (int r = 0; r < 4; ++r) {
        nj0[r] = neigh[(node_base + rq + r) * KK];
        nj1[r] = neigh[(node_base + 16 + rq + r) * KK];
    }
    s16x8 bs0 = wp[lane];
    s16x8 bs1 = wp[64 + lane];

    for (int k = 0; k < KK; ++k) {
        const int kn = (k < KK - 1) ? k + 1 : k;
        int nn0[4], nn1[4];
        #pragma unroll
        for (int r = 0; r < 4; ++r) {
            nn0[r] = neigh[(node_base + rq + r) * KK + kn];
            nn1[r] = neigh[(node_base + 16 + rq + r) * KK + kn];
        }
        const s16x8 nbs0 = wp[(kn * 2) * 64 + lane];
        const s16x8 nbs1 = wp[(kn * 2 + 1) * 64 + lane];
        {
            const f32x4 d0 = __builtin_amdgcn_mfma_f32_16x16x32_bf16(
                __builtin_bit_cast(bf16x8, afr[0]), __builtin_bit_cast(bf16x8, bs0),
                zero, 0, 0, 0);
            const f32x4 d1 = __builtin_amdgcn_mfma_f32_16x16x32_bf16(
                __builtin_bit_cast(bf16x8, afr[0]), __builtin_bit_cast(bf16x8, bs1),
                zero, 0, 0, 0);
            #pragma unroll
            for (int r = 0; r < 4; ++r) {
                __half2 v;
                v.x = __float2half(d0[r]);
                v.y = __float2half(d1[r]);
                unsafeAtomicAdd(&acc2[nj0[r] * 16 + m], v);
            }
        }
        {
            const f32x4 d0 = __builtin_amdgcn_mfma_f32_16x16x32_bf16(
                __builtin_bit_cast(bf16x8, afr[1]), __builtin_bit_cast(bf16x8, bs0),
                zero, 0, 0, 0);
            const f32x4 d1 = __builtin_amdgcn_mfma_f32_16x16x32_bf16(
                __builtin_bit_cast(bf16x8, afr[1]), __builtin_bit_cast(bf16x8, bs1),
                zero, 0, 0, 0);
            #pragma unroll
            for (int r = 0; r < 4; ++r) {
                __half2 v;
                v.x = __float2half(d0[r]);
                v.y = __float2half(d1[r]);
                unsafeAtomicAdd(&acc2[nj1[r] * 16 + m], v);
            }
        }
        bs0 = nbs0; bs1 = nbs1;
        #pragma unroll
        for (int r = 0; r < 4; ++r) { nj0[r] = nn0[r]; nj1[r] = nn1[r]; }
    }
}

__global__ __launch_bounds__(256) void stats_kernel(
    const __half2* __restrict__ acc2, float* __restrict__ stats)
{
    __shared__ float ls[16][33], ls2[16][33];
    const int tid = threadIdx.x;
    const int c2 = tid & 15, rg = tid >> 4;
    float sx = 0.f, sy = 0.f, s2x = 0.f, s2y = 0.f;
    const int row0 = blockIdx.x * 512;
    for (int it = 0; it < 32; ++it) {
        const __half2 h = acc2[(row0 + it * 16 + rg) * 16 + c2];
        const float vx = __half2float(h.x), vy = __half2float(h.y);
        sx += vx; sy += vy; s2x += vx * vx; s2y += vy * vy;
    }
    ls[rg][2 * c2] = sx;  ls[rg][2 * c2 + 1] = sy;
    ls2[rg][2 * c2] = s2x; ls2[rg][2 * c2 + 1] = s2y;
    __syncthreads();
    if (tid < 32) {
        float S = 0.f, S2 = 0.f;
        #pragma unroll
        for (int g = 0; g < 16; ++g) { S += ls[g][tid]; S2 += ls2[g][tid]; }
        atomicAdd(&stats[tid], S);
        atomicAdd(&stats[32 + tid], S2);
    }
}

__global__ __launch_bounds__(256) void bn_relu_kernel(
    const __half2* __restrict__ acc2, float* __restrict__ out,
    const float* __restrict__ stats,
    const float* __restrict__ gamma, const float* __restrict__ beta)
{
    __shared__ float sc[32], sh[32];
    const int tid = threadIdx.x;
    if (tid < 32) {
        const float mean = stats[tid] * (1.0f / NN);
        const float var  = stats[32 + tid] * (1.0f / NN) - mean * mean;
        const float s = gamma[tid] * rsqrtf(var + EPSV);
        sc[tid] = s;
        sh[tid] = beta[tid] - mean * s;
    }
    __syncthreads();
    const int idx = blockIdx.x * 256 + tid;
    const int c0 = (idx & 3) << 3;
    const __half2 h4[4] = { acc2[idx * 4], acc2[idx * 4 + 1],
                            acc2[idx * 4 + 2], acc2[idx * 4 + 3] };
    float4 o0, o1;
    o0.x = fmaxf(__half2float(h4[0].x) * sc[c0]     + sh[c0],     0.f);
    o0.y = fmaxf(__half2float(h4[0].y) * sc[c0 + 1] + sh[c0 + 1], 0.f);
    o0.z = fmaxf(__half2float(h4[1].x) * sc[c0 + 2] + sh[c0 + 2], 0.f);
    o0.w = fmaxf(__half2float(h4[1].y) * sc[c0 + 3] + sh[c0 + 3], 0.f);
    o1.x = fmaxf(__half2float(h4[2].x) * sc[c0 + 4] + sh[c0 + 4], 0.f);
    o1.y = fmaxf(__half2float(h4[2].y) * sc[c0 + 5] + sh[c0 + 5], 0.f);
    o1.z = fmaxf(__half2float(h4[3].x) * sc[c0 + 6] + sh[c0 + 6], 0.f);
    o1.w = fmaxf(__half2float(h4[3].y) * sc[c0 + 7] + sh[c0 + 7], 0.f);
    ((float4*)out)[idx * 2]     = o0;
    ((float4*)out)[idx * 2 + 1] = o1;
}

// ===========================================================================
// Tier-3 fallback (f32 atomics into d_out)
// ===========================================================================
__global__ __launch_bounds__(256) void scatter_f32_kernel(
    const float* __restrict__ data, const float* __restrict__ weight,
    const int* __restrict__ neigh, float* __restrict__ out)
{
    __shared__ unsigned short wfrag[KK * 2 * 64 * 8];
    const int tid = threadIdx.x;
    const int lane = tid & 63;
    const int wv = tid >> 6;
    const int node_base = blockIdx.x * 128;
    for (int p = tid; p < KK * 1024; p += 256) {
        const int k  = p >> 10;
        const int ci = (p >> 5) & 31;
        const int c  = p & 31;
        const unsigned short v = f2bf(weight[p]);
        const int chalf = c >> 4;
        const int fl = (c & 15) | ((ci >> 3) << 4);
        const int j = ci & 7;
        wfrag[(((k << 1) | chalf) * 64 + fl) * 8 + j] = v;
    }
    const int quad = lane >> 4;
    const int m = lane & 15;
    s16x8 afr[2];
    #pragma unroll
    for (int g = 0; g < 2; ++g) {
        const int node = node_base + wv * 32 + g * 16 + m;
        const float* src = data + node * 32 + quad * 8;
        const float4 v0 = *(const float4*)(src);
        const float4 v1 = *(const float4*)(src + 4);
        s16x8 s;
        s[0] = (short)f2bf(v0.x); s[1] = (short)f2bf(v0.y);
        s[2] = (short)f2bf(v0.z); s[3] = (short)f2bf(v0.w);
        s[4] = (short)f2bf(v1.x); s[5] = (short)f2bf(v1.y);
        s[6] = (short)f2bf(v1.z); s[7] = (short)f2bf(v1.w);
        afr[g] = s;
    }
    __syncthreads();
    const int rq = quad << 2;
    const f32x4 zero = {0.f, 0.f, 0.f, 0.f};
    for (int k = 0; k < KK; ++k) {
        int nj[2][4];
        #pragma unroll
        for (int g = 0; g < 2; ++g)
            #pragma unroll
            for (int r = 0; r < 4; ++r) {
                const int node = node_base + wv * 32 + g * 16 + rq + r;
                nj[g][r] = neigh[node * KK + k];
            }
        #pragma unroll
        for (int ch = 0; ch < 2; ++ch) {
            const s16x8 bs = *(const s16x8*)&wfrag[((((k << 1) | ch)) * 64 + lane) * 8];
            const bf16x8 bfr = __builtin_bit_cast(bf16x8, bs);
            const int c = (ch << 4) | m;
            #pragma unroll
            for (int g = 0; g < 2; ++g) {
                f32x4 a2 = __builtin_amdgcn_mfma_f32_16x16x32_bf16(
                    __builtin_bit_cast(bf16x8, afr[g]), bfr, zero, 0, 0, 0);
                #pragma unroll
                for (int r = 0; r < 4; ++r)
                    __hip_atomic_fetch_add(&out[nj[g][r] * 32 + c], a2[r],
                                           __ATOMIC_RELAXED, __HIP_MEMORY_SCOPE_AGENT);
            }
        }
    }
}

__global__ __launch_bounds__(256) void stats_f32_kernel(
    const float* __restrict__ out, float* __restrict__ stats)
{
    __shared__ float ls[256], ls2[256];
    const int tid = threadIdx.x;
    const int c = tid & 31, rg = tid >> 5;
    float s = 0.f, s2 = 0.f;
    const int row0 = blockIdx.x * 512;
    for (int it = 0; it < 64; ++it) {
        const float v = out[(row0 + it * 8 + rg) * 32 + c];
        s += v; s2 += v * v;
    }
    ls[tid] = s; ls2[tid] = s2;
    __syncthreads();
    if (tid < 32) {
        float S = 0.f, S2 = 0.f;
        #pragma unroll
        for (int r = 0; r < 8; ++r) { S += ls[r * 32 + tid]; S2 += ls2[r * 32 + tid]; }
        atomicAdd(&stats[tid], S);
        atomicAdd(&stats[32 + tid], S2);
    }
}

// ===========================================================================
extern "C" void kernel_launch(void* const* d_in, const int* in_sizes, int n_in,
                              void* d_out, int out_size, void* d_ws, size_t ws_size,
                              hipStream_t stream) {
    const float* data   = (const float*)d_in[0];
    const float* weight = (const float*)d_in[1];
    const float* gamma  = (const float*)d_in[2];
    const float* beta   = (const float*)d_in[3];
    const int*   neigh  = (const int*)d_in[4];
    float* out = (float*)d_out;
    char* ws = (char*)d_ws;
    float* stats = (float*)(ws + WS_STATS);

    if (ws_size >= WS_NEED_GATHER) {
        unsigned int*   gcnt   = (unsigned int*)(ws + WS_GCNT);
        unsigned int*   koff   = (unsigned int*)(ws + WS_KOFF);
        unsigned short* wperm  = (unsigned short*)(ws + WS_WPERM);
        unsigned int*   raw    = (unsigned int*)(ws + WS_RAW);
        unsigned int*   sorted = (unsigned int*)(ws + WS_SORT);
        unsigned short* data16 = (unsigned short*)(ws + WS_DATA16);
        hipMemsetAsync(ws, 0, 2304, stream);               // stats + gcnt
        prep_kernel<<<2156, 256, 0, stream>>>(data, weight, data16, wperm);
        partition_kernel<<<(NN * KK) / 4096, 256, 0, stream>>>(neigh, gcnt, raw);
        binsort_kernel<<<NBINS, 256, 0, stream>>>(gcnt, raw, sorted, koff);
        gathermm_kernel<<<NBINS, 256, 0, stream>>>(data16, wperm, sorted, koff, out, stats);
        bn_relu_f32_kernel<<<(NN * CC / 4) / 256, 256, 0, stream>>>(out, stats, gamma, beta);
    } else if (ws_size >= WS_NEED_T2) {
        __half2* acc2 = (__half2*)(ws + T2_ACC);
        unsigned short* wperm = (unsigned short*)(ws + T2_WPERM);
        hipMemsetAsync(ws + WS_STATS, 0, 256, stream);
        hipMemsetAsync(ws + T2_ACC, 0, (size_t)NN * CC * 2, stream);
        prep_weights_bf16_kernel<<<(KK * 1024 + 255) / 256, 256, 0, stream>>>(weight, wperm);
        scatter_kernel<<<NN / 128, 256, 0, stream>>>(data, wperm, neigh, acc2);
        stats_kernel<<<NN / 512, 256, 0, stream>>>(acc2, stats);
        bn_relu_kernel<<<(NN * CC / 8) / 256, 256, 0, stream>>>(acc2, out, stats, gamma, beta);
    } else {
        hipMemsetAsync(out, 0, (size_t)NN * CC * sizeof(float), stream);
        hipMemsetAsync(ws + WS_STATS, 0, 64 * sizeof(float), stream);
        scatter_f32_kernel<<<NN / 128, 256, 0, stream>>>(data, weight, neigh, out);
        stats_f32_kernel<<<NN / 512, 256, 0, stream>>>(out, stats);
        bn_relu_f32_kernel<<<(NN * CC / 4) / 256, 256, 0, stream>>>(out, stats, gamma, beta);
    }
}

// Round 4
// 724.998 us; speedup vs baseline: 1.0065x; 1.0065x over previous
//
#include <hip/hip_runtime.h>
#include <hip/hip_bf16.h>
#include <hip/hip_fp16.h>

#define NN 131072
#define KK 27
#define CC 32
#define EPSV 1e-5f

// ---------------------------------------------------------------------------
// Tier-1 (partitioned gather) workspace layout (bytes):
//   [0,256)       f32 stats
//   [256,2304)    u32 gcnt[512]        (bin fill counters, memset 0)
//   [2304,57600)  f16 wperm            (55296 B, MFMA B-fragment layout)
//   [57600,+8.4M) f16 data16[N][32]
//   [WS_RAW]      u32 raw[512][7680]   (bin records, unsorted; sort is in-LDS)
#define NBINS   512
#define CAPBIN  7680          // global bin capacity
#define LDSCAP  7424          // in-LDS sorted capacity (mean 6912, +6 sigma)
#define CAPB    24            // per-bin LDS staging slots in partition
#define WS_STATS   0
#define WS_GCNT    256
#define WS_WPERM   2304
#define WS_DATA16  57600
#define WS_RAW     8446208
#define WS_NEED_GATHER ((size_t)WS_RAW + (size_t)NBINS * CAPBIN * 4)   // 24.2 MB

// Tier-2 (R1 atomic-scatter, proven 271us) layout
#define T2_WPERM 256
#define T2_ACC   65536
#define WS_NEED_T2 ((size_t)T2_ACC + (size_t)NN * CC * 2)

typedef __bf16 bf16x8 __attribute__((ext_vector_type(8)));
typedef _Float16 f16x8 __attribute__((ext_vector_type(8)));
typedef short s16x8 __attribute__((ext_vector_type(8)));
typedef float f32x4 __attribute__((ext_vector_type(4)));

__device__ inline unsigned short f2bf(float f) {
    unsigned int u = __float_as_uint(f);
    u += 0x7FFF + ((u >> 16) & 1);   // round-to-nearest-even
    return (unsigned short)(u >> 16);
}
__device__ inline unsigned short f2h(float f) {
    return __builtin_bit_cast(unsigned short, __float2half(f));
}

// ===========================================================================
// Tier-1 kernels
// ===========================================================================

// Fused prep (verified R2/R3): blocks [0,2048) convert data f32->f16;
// blocks [2048,2156) permute weights into f16 MFMA B-fragment layout.
// Logical out-channel c -> MFMA ch-half (c&1) at physical column (c>>1);
// fragment element (fl, j): fl = col | ((ci>>3)<<4), j = ci&7.
__global__ __launch_bounds__(256) void prep_kernel(
    const float* __restrict__ data, const float* __restrict__ weight,
    unsigned short* __restrict__ data16, unsigned short* __restrict__ wperm)
{
    const int b = blockIdx.x;
    if (b < 2048) {
        const int tg = b * 256 + threadIdx.x;          // 8 floats each
        const float4 v0 = ((const float4*)data)[tg * 2];
        const float4 v1 = ((const float4*)data)[tg * 2 + 1];
        union { unsigned short us[8]; uint4 u4; } o;
        o.us[0] = f2h(v0.x); o.us[1] = f2h(v0.y);
        o.us[2] = f2h(v0.z); o.us[3] = f2h(v0.w);
        o.us[4] = f2h(v1.x); o.us[5] = f2h(v1.y);
        o.us[6] = f2h(v1.z); o.us[7] = f2h(v1.w);
        ((uint4*)data16)[tg] = o.u4;
    } else {
        const int p = (b - 2048) * 256 + threadIdx.x;  // < 27648 exactly
        const int k  = p >> 10;
        const int ci = (p >> 5) & 31;
        const int c  = p & 31;
        const unsigned short v = f2h(weight[p]);
        const int chalf = c & 1;
        const int col   = c >> 1;
        const int fl = col | ((ci >> 3) << 4);
        const int j = ci & 7;
        wperm[(((k << 1) | chalf) * 64 + fl) * 8 + j] = v;
    }
}

// Partition 3.54M (i,k) pairs into 512 bins of 256 output rows, via LDS
// staging so global writes are bulk runs (L2 line-merged), not random 4B
// scatters. Record: k(5b)<<25 | i(17b)<<8 | (o&255).
__global__ __launch_bounds__(256) void partition_kernel(
    const int* __restrict__ neigh, unsigned int* __restrict__ gcnt,
    unsigned int* __restrict__ raw)
{
    __shared__ unsigned int lcnt[NBINS];
    __shared__ unsigned int lbuf[NBINS * CAPB];   // 49152 B
    const int tid = threadIdx.x;
    for (int t = tid; t < NBINS; t += 256) lcnt[t] = 0;
    __syncthreads();
    const int base = blockIdx.x * 4096;
    #pragma unroll
    for (int j = 0; j < 16; ++j) {
        const int p = base + j * 256 + tid;
        const unsigned int o = (unsigned int)neigh[p];
        const unsigned int i = (unsigned int)p / 27u;
        const unsigned int k = (unsigned int)p - i * 27u;
        const unsigned int rec = (k << 25) | (i << 8) | (o & 255u);
        const unsigned int bin = o >> 8;
        const unsigned int slot = atomicAdd(&lcnt[bin], 1u);
        if (slot < CAPB) {
            lbuf[bin * CAPB + slot] = rec;
        } else {                                   // rare overflow: direct append
            const unsigned int gp = atomicAdd(&gcnt[bin], 1u);
            if (gp < CAPBIN) raw[(size_t)bin * CAPBIN + gp] = rec;
        }
    }
    __syncthreads();
    for (int b2 = tid; b2 < NBINS; b2 += 256) {
        unsigned int nb = lcnt[b2]; if (nb > CAPB) nb = CAPB;
        if (nb == 0) continue;
        const unsigned int gbase = atomicAdd(&gcnt[b2], nb);
        for (unsigned int s = 0; s < nb; ++s) {
            const unsigned int gp = gbase + s;
            if (gp < CAPBIN) raw[(size_t)b2 * CAPBIN + gp] = lbuf[b2 * CAPB + s];
        }
    }
}

// Fused binsort + gather-GEMM per bin. 512 threads = 8 waves, grid 512
// -> 2 blocks/CU, 16 waves/CU.
// Phase 1: counting-sort the bin's records by tap k into LDS (records then
//          only ever read via lgkmcnt -> data gathers own vmcnt exclusively).
// Phase 2: waves split taps (k = wv+8j). Per 16-record step: A-rows = 16
//          gathered data16 lines (depth-3 register ring), B = wperm[k]
//          (L2-hot), one f16 MFMA pair, C scattered into LDS f32 accumulator
//          with ds_add; the destination row o comes from __shfl of the
//          in-register record -- no waited VMEM in the loop besides the
//          pipelined gather.
// Epilogue: rows written once (streaming), BN stats fused (64 atomics/blk).
__global__ __launch_bounds__(512) void gathermm_kernel(
    const unsigned short* __restrict__ data16,
    const unsigned short* __restrict__ wperm,
    const unsigned int* __restrict__ gcnt, const unsigned int* __restrict__ raw,
    float* __restrict__ out, float* __restrict__ stats)
{
    __shared__ float accS[256 * 33];            // 33792 B
    __shared__ unsigned int slds[LDSCAP];       // 29696 B
    __shared__ unsigned int hist[KK + 1];       // CSR offsets after prefix
    __shared__ unsigned int curs[KK];

    const int tid = threadIdx.x;
    const int bb = blockIdx.x;

    for (int t = tid; t < 256 * 33; t += 512) accS[t] = 0.f;
    if (tid < KK + 1) hist[tid] = 0;
    __syncthreads();

    unsigned int n = gcnt[bb];
    if (n > CAPBIN) n = CAPBIN;
    if (n > LDSCAP) n = LDSCAP;
    const unsigned int* rp = raw + (size_t)bb * CAPBIN;

    for (unsigned int t = tid; t < n; t += 512)
        atomicAdd(&hist[rp[t] >> 25], 1u);
    __syncthreads();
    if (tid == 0) {
        unsigned int run = 0;
        for (int j = 0; j < KK; ++j) {
            const unsigned int h = hist[j];
            hist[j] = run; curs[j] = run; run += h;
        }
        hist[KK] = run;
    }
    __syncthreads();
    for (unsigned int t = tid; t < n; t += 512) {
        const unsigned int r = rp[t];
        const unsigned int pos = atomicAdd(&curs[r >> 25], 1u);
        slds[pos] = r & 0x01FFFFFFu;            // i<<8 | o_local
    }
    __syncthreads();

    // ---- phase 2: per-tap MFMA over LDS-sorted records ----
    const int lane = tid & 63, wv = tid >> 6;   // 8 waves
    const int q = lane >> 4, m = lane & 15;
    const uint4* wq = (const uint4*)wperm;
    const uint4* dq = (const uint4*)data16;
    const f32x4 zero = {0.f, 0.f, 0.f, 0.f};

    for (int k = wv; k < KK; k += 8) {
        const int s0  = (int)hist[k];
        const int len = (int)hist[k + 1] - s0;
        if (len <= 0) continue;
        const int last = len - 1;
        const uint4 bf0 = wq[(k * 2) * 64 + lane];
        const uint4 bf1 = wq[(k * 2 + 1) * 64 + lane];

        // rec + data rings (depth 3): recs via lgkm (LDS), data via vmcnt only
        int i0 = m;            unsigned int r0 = slds[s0 + (i0 < last ? i0 : last)];
        int i1 = 16 + m;       unsigned int r1 = slds[s0 + (i1 < last ? i1 : last)];
        int i2 = 32 + m;       unsigned int r2v = slds[s0 + (i2 < last ? i2 : last)];
        uint4 dv0 = dq[((r0  >> 8) << 2) | q];
        uint4 dv1 = dq[((r1  >> 8) << 2) | q];
        uint4 dv2 = dq[((r2v >> 8) << 2) | q];

        const int nsteps = (len + 15) >> 4;
        for (int t = 0; t < nsteps; ++t) {
            const int i3 = 16 * t + 48 + m;
            const unsigned int r3 = slds[s0 + (i3 < last ? i3 : last)];
            const uint4 dv3 = dq[((r3 >> 8) << 2) | q];

            const f32x4 d0 = __builtin_amdgcn_mfma_f32_16x16x32_f16(
                __builtin_bit_cast(f16x8, dv0), __builtin_bit_cast(f16x8, bf0),
                zero, 0, 0, 0);
            const f32x4 d1 = __builtin_amdgcn_mfma_f32_16x16x32_f16(
                __builtin_bit_cast(f16x8, dv0), __builtin_bit_cast(f16x8, bf1),
                zero, 0, 0, 0);
            // C row 4q+r <-> record 16t+4q+r; columns: d0 -> ch 2m, d1 -> 2m+1.
            // Destination row o from the in-register rec ring via shuffle.
            #pragma unroll
            for (int r2i = 0; r2i < 4; ++r2i) {
                const unsigned int rr =
                    (unsigned int)__shfl((int)r0, 4 * q + r2i);
                const int jr = 16 * t + 4 * q + r2i;
                if (jr < len) {
                    const int o = (int)(rr & 255u);
                    atomicAdd(&accS[o * 33 + 2 * m],     d0[r2i]);
                    atomicAdd(&accS[o * 33 + 2 * m + 1], d1[r2i]);
                }
            }
            r0 = r1; r1 = r2v; r2v = r3;
            dv0 = dv1; dv1 = dv2; dv2 = dv3;
        }
    }
    __syncthreads();

    // ---- epilogue: write rows once + fused BN stats ----
    {
        const int row = tid >> 1, half = (tid & 1) << 4;
        const float* ar = &accS[row * 33 + half];
        float4* op = (float4*)(out + ((size_t)(bb * 256 + row)) * 32 + half);
        #pragma unroll
        for (int c4 = 0; c4 < 4; ++c4) {
            float4 v;
            v.x = ar[c4 * 4]; v.y = ar[c4 * 4 + 1];
            v.z = ar[c4 * 4 + 2]; v.w = ar[c4 * 4 + 3];
            op[c4] = v;
        }
    }
    {
        float* ps  = (float*)slds;            // reuse: 16x32 sums
        float* ps2 = ps + 512;                //        16x32 sumsq
        const int cc = tid & 31, rg = tid >> 5;   // rg 0..15
        float s = 0.f, s2 = 0.f;
        for (int rr = rg; rr < 256; rr += 16) {
            const float v = accS[rr * 33 + cc];
            s += v; s2 += v * v;
        }
        ps[rg * 32 + cc] = s; ps2[rg * 32 + cc] = s2;
        __syncthreads();
        if (tid < 32) {
            float S = 0.f, S2 = 0.f;
            #pragma unroll
            for (int g = 0; g < 16; ++g) { S += ps[g * 32 + tid]; S2 += ps2[g * 32 + tid]; }
            atomicAdd(&stats[tid], S);
            atomicAdd(&stats[32 + tid], S2);
        }
    }
}

// BN+ReLU in place on f32 out (tier-1 and tier-3)
__global__ __launch_bounds__(256) void bn_relu_f32_kernel(
    float* __restrict__ out, const float* __restrict__ stats,
    const float* __restrict__ gamma, const float* __restrict__ beta)
{
    __shared__ float sc[32], sh[32];
    const int tid = threadIdx.x;
    if (tid < 32) {
        const float mean = stats[tid] * (1.0f / NN);
        const float var  = stats[32 + tid] * (1.0f / NN) - mean * mean;
        const float s = gamma[tid] * rsqrtf(var + EPSV);
        sc[tid] = s;
        sh[tid] = beta[tid] - mean * s;
    }
    __syncthreads();
    const int idx = blockIdx.x * 256 + tid;
    float4 v = ((float4*)out)[idx];
    const int cb = (idx & 7) << 2;
    v.x = fmaxf(v.x * sc[cb]     + sh[cb],     0.f);
    v.y = fmaxf(v.y * sc[cb + 1] + sh[cb + 1], 0.f);
    v.z = fmaxf(v.z * sc[cb + 2] + sh[cb + 2], 0.f);
    v.w = fmaxf(v.w * sc[cb + 3] + sh[cb + 3], 0.f);
    ((float4*)out)[idx] = v;
}

// ===========================================================================
// Tier-2: R1 atomic-scatter path (proven at 271 us)
// ===========================================================================
__global__ __launch_bounds__(256) void prep_weights_bf16_kernel(
    const float* __restrict__ weight, unsigned short* __restrict__ wperm)
{
    const int p = blockIdx.x * 256 + threadIdx.x;
    if (p >= KK * 1024) return;
    const int k  = p >> 10;
    const int ci = (p >> 5) & 31;
    const int c  = p & 31;
    const unsigned short v = f2bf(weight[p]);
    const int chalf = c & 1;
    const int col   = c >> 1;
    const int fl = col | ((ci >> 3) << 4);
    const int j = ci & 7;
    wperm[(((k << 1) | chalf) * 64 + fl) * 8 + j] = v;
}

__global__ __launch_bounds__(256) void scatter_kernel(
    const float* __restrict__ data, const unsigned short* __restrict__ wperm,
    const int* __restrict__ neigh, __half2* __restrict__ acc2)
{
    const int tid = threadIdx.x;
    const int lane = tid & 63;
    const int wv = tid >> 6;
    const int node_base = blockIdx.x * 128 + wv * 32;
    const int quad = lane >> 4;
    const int m = lane & 15;
    const int rq = quad << 2;

    s16x8 afr[2];
    #pragma unroll
    for (int g = 0; g < 2; ++g) {
        const int node = node_base + g * 16 + m;
        const float* src = data + node * 32 + quad * 8;
        const float4 v0 = *(const float4*)(src);
        const float4 v1 = *(const float4*)(src + 4);
        s16x8 s;
        s[0] = (short)f2bf(v0.x); s[1] = (short)f2bf(v0.y);
        s[2] = (short)f2bf(v0.z); s[3] = (short)f2bf(v0.w);
        s[4] = (short)f2bf(v1.x); s[5] = (short)f2bf(v1.y);
        s[6] = (short)f2bf(v1.z); s[7] = (short)f2bf(v1.w);
        afr[g] = s;
    }

    const s16x8* wp = (const s16x8*)wperm;
    const f32x4 zero = {0.f, 0.f, 0.f, 0.f};

    int nj0[4], nj1[4];
    #pragma unroll
    for (int r = 0; r < 4; ++r) {
        nj0[r] = neigh[(node_base + rq + r) * KK];
        nj1[r] = neigh[(node_base + 16 + rq + r) * KK];
    }
    s16x8 bs0 = wp[lane];
    s16x8 bs1 = wp[64 + lane];

    for (int k = 0; k < KK; ++k) {
        const int kn = (k < KK - 1) ? k + 1 : k;
        int nn0[4], nn1[4];
        #pragma unroll
        for (int r = 0; r < 4; ++r) {
            nn0[r] = neigh[(node_base + rq + r) * KK + kn];
            nn1[r] = neigh[(node_base + 16 + rq + r) * KK + kn];
        }
        const s16x8 nbs0 = wp[(kn * 2) * 64 + lane];
        const s16x8 nbs1 = wp[(kn * 2 + 1) * 64 + lane];
        {
            const f32x4 d0 = __builtin_amdgcn_mfma_f32_16x16x32_bf16(
                __builtin_bit_cast(bf16x8, afr[0]), __builtin_bit_cast(bf16x8, bs0),
                zero, 0, 0, 0);
            const f32x4 d1 = __builtin_amdgcn_mfma_f32_16x16x32_bf16(
                __builtin_bit_cast(bf16x8, afr[0]), __builtin_bit_cast(bf16x8, bs1),
                zero, 0, 0, 0);
            #pragma unroll
            for (int r = 0; r < 4; ++r) {
                __half2 v;
                v.x = __float2half(d0[r]);
                v.y = __float2half(d1[r]);
                unsafeAtomicAdd(&acc2[nj0[r] * 16 + m], v);
            }
        }
        {
            const f32x4 d0 = __builtin_amdgcn_mfma_f32_16x16x32_bf16(
                __builtin_bit_cast(bf16x8, afr[1]), __builtin_bit_cast(bf16x8, bs0),
                zero, 0, 0, 0);
            const f32x4 d1 = __builtin_amdgcn_mfma_f32_16x16x32_bf16(
                __builtin_bit_cast(bf16x8, afr[1]), __builtin_bit_cast(bf16x8, bs1),
                zero, 0, 0, 0);
            #pragma unroll
            for (int r = 0; r < 4; ++r) {
                __half2 v;
                v.x = __float2half(d0[r]);
                v.y = __float2half(d1[r]);
                unsafeAtomicAdd(&acc2[nj1[r] * 16 + m], v);
            }
        }
        bs0 = nbs0; bs1 = nbs1;
        #pragma unroll
        for (int r = 0; r < 4; ++r) { nj0[r] = nn0[r]; nj1[r] = nn1[r]; }
    }
}

__global__ __launch_bounds__(256) void stats_kernel(
    const __half2* __restrict__ acc2, float* __restrict__ stats)
{
    __shared__ float ls[16][33], ls2[16][33];
    const int tid = threadIdx.x;
    const int c2 = tid & 15, rg = tid >> 4;
    float sx = 0.f, sy = 0.f, s2x = 0.f, s2y = 0.f;
    const int row0 = blockIdx.x * 512;
    for (int it = 0; it < 32; ++it) {
        const __half2 h = acc2[(row0 + it * 16 + rg) * 16 + c2];
        const float vx = __half2float(h.x), vy = __half2float(h.y);
        sx += vx; sy += vy; s2x += vx * vx; s2y += vy * vy;
    }
    ls[rg][2 * c2] = sx;  ls[rg][2 * c2 + 1] = sy;
    ls2[rg][2 * c2] = s2x; ls2[rg][2 * c2 + 1] = s2y;
    __syncthreads();
    if (tid < 32) {
        float S = 0.f, S2 = 0.f;
        #pragma unroll
        for (int g = 0; g < 16; ++g) { S += ls[g][tid]; S2 += ls2[g][tid]; }
        atomicAdd(&stats[tid], S);
        atomicAdd(&stats[32 + tid], S2);
    }
}

__global__ __launch_bounds__(256) void bn_relu_kernel(
    const __half2* __restrict__ acc2, float* __restrict__ out,
    const float* __restrict__ stats,
    const float* __restrict__ gamma, const float* __restrict__ beta)
{
    __shared__ float sc[32], sh[32];
    const int tid = threadIdx.x;
    if (tid < 32) {
        const float mean = stats[tid] * (1.0f / NN);
        const float var  = stats[32 + tid] * (1.0f / NN) - mean * mean;
        const float s = gamma[tid] * rsqrtf(var + EPSV);
        sc[tid] = s;
        sh[tid] = beta[tid] - mean * s;
    }
    __syncthreads();
    const int idx = blockIdx.x * 256 + tid;
    const int c0 = (idx & 3) << 3;
    const __half2 h4[4] = { acc2[idx * 4], acc2[idx * 4 + 1],
                            acc2[idx * 4 + 2], acc2[idx * 4 + 3] };
    float4 o0, o1;
    o0.x = fmaxf(__half2float(h4[0].x) * sc[c0]     + sh[c0],     0.f);
    o0.y = fmaxf(__half2float(h4[0].y) * sc[c0 + 1] + sh[c0 + 1], 0.f);
    o0.z = fmaxf(__half2float(h4[1].x) * sc[c0 + 2] + sh[c0 + 2], 0.f);
    o0.w = fmaxf(__half2float(h4[1].y) * sc[c0 + 3] + sh[c0 + 3], 0.f);
    o1.x = fmaxf(__half2float(h4[2].x) * sc[c0 + 4] + sh[c0 + 4], 0.f);
    o1.y = fmaxf(__half2float(h4[2].y) * sc[c0 + 5] + sh[c0 + 5], 0.f);
    o1.z = fmaxf(__half2float(h4[3].x) * sc[c0 + 6] + sh[c0 + 6], 0.f);
    o1.w = fmaxf(__half2float(h4[3].y) * sc[c0 + 7] + sh[c0 + 7], 0.f);
    ((float4*)out)[idx * 2]     = o0;
    ((float4*)out)[idx * 2 + 1] = o1;
}

// ===========================================================================
// Tier-3 fallback (f32 atomics into d_out)
// ===========================================================================
__global__ __launch_bounds__(256) void scatter_f32_kernel(
    const float* __restrict__ data, const float* __restrict__ weight,
    const int* __restrict__ neigh, float* __restrict__ out)
{
    __shared__ unsigned short wfrag[KK * 2 * 64 * 8];
    const int tid = threadIdx.x;
    const int lane = tid & 63;
    const int wv = tid >> 6;
    const int node_base = blockIdx.x * 128;
    for (int p = tid; p < KK * 1024; p += 256) {
        const int k  = p >> 10;
        const int ci = (p >> 5) & 31;
        const int c  = p & 31;
        const unsigned short v = f2bf(weight[p]);
        const int chalf = c >> 4;
        const int fl = (c & 15) | ((ci >> 3) << 4);
        const int j = ci & 7;
        wfrag[(((k << 1) | chalf) * 64 + fl) * 8 + j] = v;
    }
    const int quad = lane >> 4;
    const int m = lane & 15;
    s16x8 afr[2];
    #pragma unroll
    for (int g = 0; g < 2; ++g) {
        const int node = node_base + wv * 32 + g * 16 + m;
        const float* src = data + node * 32 + quad * 8;
        const float4 v0 = *(const float4*)(src);
        const float4 v1 = *(const float4*)(src + 4);
        s16x8 s;
        s[0] = (short)f2bf(v0.x); s[1] = (short)f2bf(v0.y);
        s[2] = (short)f2bf(v0.z); s[3] = (short)f2bf(v0.w);
        s[4] = (short)f2bf(v1.x); s[5] = (short)f2bf(v1.y);
        s[6] = (short)f2bf(v1.z); s[7] = (short)f2bf(v1.w);
        afr[g] = s;
    }
    __syncthreads();
    const int rq = quad << 2;
    const f32x4 zero = {0.f, 0.f, 0.f, 0.f};
    for (int k = 0; k < KK; ++k) {
        int nj[2][4];
        #pragma unroll
        for (int g = 0; g < 2; ++g)
            #pragma unroll
            for (int r = 0; r < 4; ++r) {
                const int node = node_base + wv * 32 + g * 16 + rq + r;
                nj[g][r] = neigh[node * KK + k];
            }
        #pragma unroll
        for (int ch = 0; ch < 2; ++ch) {
            const s16x8 bs = *(const s16x8*)&wfrag[((((k << 1) | ch)) * 64 + lane) * 8];
            const bf16x8 bfr = __builtin_bit_cast(bf16x8, bs);
            const int c = (ch << 4) | m;
            #pragma unroll
            for (int g = 0; g < 2; ++g) {
                f32x4 a2 = __builtin_amdgcn_mfma_f32_16x16x32_bf16(
                    __builtin_bit_cast(bf16x8, afr[g]), bfr, zero, 0, 0, 0);
                #pragma unroll
                for (int r = 0; r < 4; ++r)
                    __hip_atomic_fetch_add(&out[nj[g][r] * 32 + c], a2[r],
                                           __ATOMIC_RELAXED, __HIP_MEMORY_SCOPE_AGENT);
            }
        }
    }
}

__global__ __launch_bounds__(256) void stats_f32_kernel(
    const float* __restrict__ out, float* __restrict__ stats)
{
    __shared__ float ls[256], ls2[256];
    const int tid = threadIdx.x;
    const int c = tid & 31, rg = tid >> 5;
    float s = 0.f, s2 = 0.f;
    const int row0 = blockIdx.x * 512;
    for (int it = 0; it < 64; ++it) {
        const float v = out[(row0 + it * 8 + rg) * 32 + c];
        s += v; s2 += v * v;
    }
    ls[tid] = s; ls2[tid] = s2;
    __syncthreads();
    if (tid < 32) {
        float S = 0.f, S2 = 0.f;
        #pragma unroll
        for (int r = 0; r < 8; ++r) { S += ls[r * 32 + tid]; S2 += ls2[r * 32 + tid]; }
        atomicAdd(&stats[tid], S);
        atomicAdd(&stats[32 + tid], S2);
    }
}

// ===========================================================================
extern "C" void kernel_launch(void* const* d_in, const int* in_sizes, int n_in,
                              void* d_out, int out_size, void* d_ws, size_t ws_size,
                              hipStream_t stream) {
    const float* data   = (const float*)d_in[0];
    const float* weight = (const float*)d_in[1];
    const float* gamma  = (const float*)d_in[2];
    const float* beta   = (const float*)d_in[3];
    const int*   neigh  = (const int*)d_in[4];
    float* out = (float*)d_out;
    char* ws = (char*)d_ws;
    float* stats = (float*)(ws + WS_STATS);

    if (ws_size >= WS_NEED_GATHER) {
        unsigned int*   gcnt   = (unsigned int*)(ws + WS_GCNT);
        unsigned short* wperm  = (unsigned short*)(ws + WS_WPERM);
        unsigned short* data16 = (unsigned short*)(ws + WS_DATA16);
        unsigned int*   raw    = (unsigned int*)(ws + WS_RAW);
        hipMemsetAsync(ws, 0, 2304, stream);               // stats + gcnt
        prep_kernel<<<2156, 256, 0, stream>>>(data, weight, data16, wperm);
        partition_kernel<<<(NN * KK) / 4096, 256, 0, stream>>>(neigh, gcnt, raw);
        gathermm_kernel<<<NBINS, 512, 0, stream>>>(data16, wperm, gcnt, raw, out, stats);
        bn_relu_f32_kernel<<<(NN * CC / 4) / 256, 256, 0, stream>>>(out, stats, gamma, beta);
    } else if (ws_size >= WS_NEED_T2) {
        __half2* acc2 = (__half2*)(ws + T2_ACC);
        unsigned short* wperm = (unsigned short*)(ws + T2_WPERM);
        hipMemsetAsync(ws + WS_STATS, 0, 256, stream);
        hipMemsetAsync(ws + T2_ACC, 0, (size_t)NN * CC * 2, stream);
        prep_weights_bf16_kernel<<<(KK * 1024 + 255) / 256, 256, 0, stream>>>(weight, wperm);
        scatter_kernel<<<NN / 128, 256, 0, stream>>>(data, wperm, neigh, acc2);
        stats_kernel<<<NN / 512, 256, 0, stream>>>(acc2, stats);
        bn_relu_kernel<<<(NN * CC / 8) / 256, 256, 0, stream>>>(acc2, out, stats, gamma, beta);
    } else {
        hipMemsetAsync(out, 0, (size_t)NN * CC * sizeof(float), stream);
        hipMemsetAsync(ws + WS_STATS, 0, 64 * sizeof(float), stream);
        scatter_f32_kernel<<<NN / 128, 256, 0, stream>>>(data, weight, neigh, out);
        stats_f32_kernel<<<NN / 512, 256, 0, stream>>>(out, stats);
        bn_relu_f32_kernel<<<(NN * CC / 4) / 256, 256, 0, stream>>>(out, stats, gamma, beta);
    }
}

// Round 5
// 426.617 us; speedup vs baseline: 1.7104x; 1.6994x over previous
//
#include <hip/hip_runtime.h>
#include <hip/hip_cooperative_groups.h>
#include <hip/hip_bf16.h>
#include <hip/hip_fp16.h>

namespace cg = cooperative_groups;

#define NN 131072
#define KK 27
#define CC 32
#define EPSV 1e-5f

// Unified workspace layout (bytes):
//   [0,256)        f32 stats (sum, sumsq per channel)
//   [512,+8.4M)    f16 accumulator  (NN x 32 ch)
//   [WS_WPERM]     bf16 permuted weights (55296 B)
#define WS_STATS 0
#define WS_ACC   512
#define WS_WPERM (512 + (size_t)NN * CC * 2)
#define WS_NEEDED (WS_WPERM + 55296)

typedef __bf16 bf16x8 __attribute__((ext_vector_type(8)));
typedef short s16x8 __attribute__((ext_vector_type(8)));
typedef float f32x4 __attribute__((ext_vector_type(4)));

__device__ inline unsigned short f2bf(float f) {
    unsigned int u = __float_as_uint(f);
    u += 0x7FFF + ((u >> 16) & 1);   // round-to-nearest-even
    return (unsigned short)(u >> 16);
}

// ---------------------------------------------------------------------------
// The scatter wave body (R1-proven, 177us): MFMA per tap, pk-f16 atomics.
// Channel permutation: logical out-channel c computed by MFMA ch-half (c&1)
// at physical column (c>>1) -> one __half2 pack + one atomic per row-pair,
// 16 lanes of a quad cover one contiguous 64B destination line.
__device__ inline void scatter_body(
    const float* __restrict__ data, const unsigned short* __restrict__ wperm,
    const int* __restrict__ neigh, __half2* __restrict__ acc2,
    int node_base, int lane)
{
    const int quad = lane >> 4;
    const int m = lane & 15;
    const int rq = quad << 2;

    s16x8 afr[2];
    #pragma unroll
    for (int g = 0; g < 2; ++g) {
        const int node = node_base + g * 16 + m;
        const float* src = data + node * 32 + quad * 8;
        const float4 v0 = *(const float4*)(src);
        const float4 v1 = *(const float4*)(src + 4);
        s16x8 s;
        s[0] = (short)f2bf(v0.x); s[1] = (short)f2bf(v0.y);
        s[2] = (short)f2bf(v0.z); s[3] = (short)f2bf(v0.w);
        s[4] = (short)f2bf(v1.x); s[5] = (short)f2bf(v1.y);
        s[6] = (short)f2bf(v1.z); s[7] = (short)f2bf(v1.w);
        afr[g] = s;
    }

    const s16x8* wp = (const s16x8*)wperm;
    const f32x4 zero = {0.f, 0.f, 0.f, 0.f};

    int nj0[4], nj1[4];
    #pragma unroll
    for (int r = 0; r < 4; ++r) {
        nj0[r] = neigh[(node_base + rq + r) * KK];
        nj1[r] = neigh[(node_base + 16 + rq + r) * KK];
    }
    s16x8 bs0 = wp[lane];
    s16x8 bs1 = wp[64 + lane];

    for (int k = 0; k < KK; ++k) {
        const int kn = (k < KK - 1) ? k + 1 : k;
        int nn0[4], nn1[4];
        #pragma unroll
        for (int r = 0; r < 4; ++r) {
            nn0[r] = neigh[(node_base + rq + r) * KK + kn];
            nn1[r] = neigh[(node_base + 16 + rq + r) * KK + kn];
        }
        const s16x8 nbs0 = wp[(kn * 2) * 64 + lane];
        const s16x8 nbs1 = wp[(kn * 2 + 1) * 64 + lane];
        {
            const f32x4 d0 = __builtin_amdgcn_mfma_f32_16x16x32_bf16(
                __builtin_bit_cast(bf16x8, afr[0]), __builtin_bit_cast(bf16x8, bs0),
                zero, 0, 0, 0);
            const f32x4 d1 = __builtin_amdgcn_mfma_f32_16x16x32_bf16(
                __builtin_bit_cast(bf16x8, afr[0]), __builtin_bit_cast(bf16x8, bs1),
                zero, 0, 0, 0);
            #pragma unroll
            for (int r = 0; r < 4; ++r) {
                __half2 v;
                v.x = __float2half(d0[r]);
                v.y = __float2half(d1[r]);
                unsafeAtomicAdd(&acc2[nj0[r] * 16 + m], v);
            }
        }
        {
            const f32x4 d0 = __builtin_amdgcn_mfma_f32_16x16x32_bf16(
                __builtin_bit_cast(bf16x8, afr[1]), __builtin_bit_cast(bf16x8, bs0),
                zero, 0, 0, 0);
            const f32x4 d1 = __builtin_amdgcn_mfma_f32_16x16x32_bf16(
                __builtin_bit_cast(bf16x8, afr[1]), __builtin_bit_cast(bf16x8, bs1),
                zero, 0, 0, 0);
            #pragma unroll
            for (int r = 0; r < 4; ++r) {
                __half2 v;
                v.x = __float2half(d0[r]);
                v.y = __float2half(d1[r]);
                unsafeAtomicAdd(&acc2[nj1[r] * 16 + m], v);
            }
        }
        bs0 = nbs0; bs1 = nbs1;
        #pragma unroll
        for (int r = 0; r < 4; ++r) { nj0[r] = nn0[r]; nj1[r] = nn1[r]; }
    }
}

// ---------------------------------------------------------------------------
// Fused cooperative kernel: prep -> sync -> scatter -> sync -> stats -> sync
// -> bn+relu. 512 blocks x 512 threads (2 blocks/CU co-resident).
// Replaces 4 dispatches + their inter-dispatch gaps with 3 grid.sync()s.
// Visibility: acc2/stats written only via device-scope atomics (coherent
// point); wperm plain stores are published by grid.sync's agent-scope
// release (L2 writeback) / acquire (invalidate).
__global__ __launch_bounds__(512, 4) void fused_kernel(
    const float* __restrict__ data, const float* __restrict__ weight,
    const float* __restrict__ gamma, const float* __restrict__ beta,
    const int* __restrict__ neigh, unsigned short* __restrict__ wperm,
    __half2* __restrict__ acc2, float* __restrict__ stats,
    float* __restrict__ out)
{
    cg::grid_group grid = cg::this_grid();
    const int tid = threadIdx.x;
    const int bb = blockIdx.x;

    __shared__ float psum[16][32], psq[16][32];   // stats partials
    __shared__ float sc[32], sh[32];              // bn scale/shift

    // ---- P0: build bf16 wperm (blocks 0..53 cover 27648 elems) ----
    {
        const int p = bb * 512 + tid;
        if (p < KK * 1024) {
            const int k  = p >> 10;
            const int ci = (p >> 5) & 31;
            const int c  = p & 31;
            const unsigned short v = f2bf(weight[p]);
            const int chalf = c & 1;
            const int col   = c >> 1;
            const int fl = col | ((ci >> 3) << 4);
            const int j = ci & 7;
            wperm[(((k << 1) | chalf) * 64 + fl) * 8 + j] = v;
        }
    }
    grid.sync();

    // ---- P1: scatter (8 waves x 32 nodes = 256 nodes/block) ----
    {
        const int lane = tid & 63, wv = tid >> 6;
        scatter_body(data, wperm, neigh, acc2, bb * 256 + wv * 32, lane);
    }
    grid.sync();

    // ---- P2: per-channel sum/sumsq over this block's 256 rows ----
    {
        const int c = tid & 31, rg = tid >> 5;    // 16 row-groups x 32 ch
        float s = 0.f, s2 = 0.f;
        #pragma unroll
        for (int i = 0; i < 16; ++i) {
            const int row = bb * 256 + rg + 16 * i;
            const __half2 h = acc2[row * 16 + (c >> 1)];
            const float v = __half2float((c & 1) ? __high2half(h) : __low2half(h));
            s += v; s2 += v * v;
        }
        psum[rg][c] = s; psq[rg][c] = s2;
        __syncthreads();
        if (tid < 32) {
            float S = 0.f, S2 = 0.f;
            #pragma unroll
            for (int g = 0; g < 16; ++g) { S += psum[g][tid]; S2 += psq[g][tid]; }
            atomicAdd(&stats[tid], S);
            atomicAdd(&stats[32 + tid], S2);
        }
    }
    grid.sync();

    // ---- P3: bn + relu over this block's 256 rows ----
    {
        if (tid < 32) {
            const float mean = stats[tid] * (1.0f / NN);
            const float var  = stats[32 + tid] * (1.0f / NN) - mean * mean;
            const float s = gamma[tid] * rsqrtf(var + EPSV);
            sc[tid] = s;
            sh[tid] = beta[tid] - mean * s;
        }
        __syncthreads();
        const int row = bb * 256 + (tid >> 1);
        const int half = tid & 1;
        const __half2* ap = acc2 + row * 16 + half * 8;   // 16 channels
        const int c0 = half * 16;
        float4 o0, o1, o2, o3;
        o0.x = fmaxf(__half2float(ap[0].x) * sc[c0]      + sh[c0],      0.f);
        o0.y = fmaxf(__half2float(ap[0].y) * sc[c0 + 1]  + sh[c0 + 1],  0.f);
        o0.z = fmaxf(__half2float(ap[1].x) * sc[c0 + 2]  + sh[c0 + 2],  0.f);
        o0.w = fmaxf(__half2float(ap[1].y) * sc[c0 + 3]  + sh[c0 + 3],  0.f);
        o1.x = fmaxf(__half2float(ap[2].x) * sc[c0 + 4]  + sh[c0 + 4],  0.f);
        o1.y = fmaxf(__half2float(ap[2].y) * sc[c0 + 5]  + sh[c0 + 5],  0.f);
        o1.z = fmaxf(__half2float(ap[3].x) * sc[c0 + 6]  + sh[c0 + 6],  0.f);
        o1.w = fmaxf(__half2float(ap[3].y) * sc[c0 + 7]  + sh[c0 + 7],  0.f);
        o2.x = fmaxf(__half2float(ap[4].x) * sc[c0 + 8]  + sh[c0 + 8],  0.f);
        o2.y = fmaxf(__half2float(ap[4].y) * sc[c0 + 9]  + sh[c0 + 9],  0.f);
        o2.z = fmaxf(__half2float(ap[5].x) * sc[c0 + 10] + sh[c0 + 10], 0.f);
        o2.w = fmaxf(__half2float(ap[5].y) * sc[c0 + 11] + sh[c0 + 11], 0.f);
        o3.x = fmaxf(__half2float(ap[6].x) * sc[c0 + 12] + sh[c0 + 12], 0.f);
        o3.y = fmaxf(__half2float(ap[6].y) * sc[c0 + 13] + sh[c0 + 13], 0.f);
        o3.z = fmaxf(__half2float(ap[7].x) * sc[c0 + 14] + sh[c0 + 14], 0.f);
        o3.w = fmaxf(__half2float(ap[7].y) * sc[c0 + 15] + sh[c0 + 15], 0.f);
        float4* op = (float4*)(out + (size_t)row * 32 + c0);
        op[0] = o0; op[1] = o1; op[2] = o2; op[3] = o3;
    }
}

// ===========================================================================
// Fallback tier: R1 5-launch path (proven 271us), same workspace layout.
// ===========================================================================
__global__ __launch_bounds__(256) void prep_weights_bf16_kernel(
    const float* __restrict__ weight, unsigned short* __restrict__ wperm)
{
    const int p = blockIdx.x * 256 + threadIdx.x;
    if (p >= KK * 1024) return;
    const int k  = p >> 10;
    const int ci = (p >> 5) & 31;
    const int c  = p & 31;
    const unsigned short v = f2bf(weight[p]);
    const int chalf = c & 1;
    const int col   = c >> 1;
    const int fl = col | ((ci >> 3) << 4);
    const int j = ci & 7;
    wperm[(((k << 1) | chalf) * 64 + fl) * 8 + j] = v;
}

__global__ __launch_bounds__(256) void scatter_kernel(
    const float* __restrict__ data, const unsigned short* __restrict__ wperm,
    const int* __restrict__ neigh, __half2* __restrict__ acc2)
{
    const int tid = threadIdx.x;
    scatter_body(data, wperm, neigh, acc2,
                 blockIdx.x * 128 + (tid >> 6) * 32, tid & 63);
}

__global__ __launch_bounds__(256) void stats_kernel(
    const __half2* __restrict__ acc2, float* __restrict__ stats)
{
    __shared__ float ls[16][33], ls2[16][33];
    const int tid = threadIdx.x;
    const int c2 = tid & 15, rg = tid >> 4;
    float sx = 0.f, sy = 0.f, s2x = 0.f, s2y = 0.f;
    const int row0 = blockIdx.x * 512;
    for (int it = 0; it < 32; ++it) {
        const __half2 h = acc2[(row0 + it * 16 + rg) * 16 + c2];
        const float vx = __half2float(h.x), vy = __half2float(h.y);
        sx += vx; sy += vy; s2x += vx * vx; s2y += vy * vy;
    }
    ls[rg][2 * c2] = sx;  ls[rg][2 * c2 + 1] = sy;
    ls2[rg][2 * c2] = s2x; ls2[rg][2 * c2 + 1] = s2y;
    __syncthreads();
    if (tid < 32) {
        float S = 0.f, S2 = 0.f;
        #pragma unroll
        for (int g = 0; g < 16; ++g) { S += ls[g][tid]; S2 += ls2[g][tid]; }
        atomicAdd(&stats[tid], S);
        atomicAdd(&stats[32 + tid], S2);
    }
}

__global__ __launch_bounds__(256) void bn_relu_kernel(
    const __half2* __restrict__ acc2, float* __restrict__ out,
    const float* __restrict__ stats,
    const float* __restrict__ gamma, const float* __restrict__ beta)
{
    __shared__ float sc[32], sh[32];
    const int tid = threadIdx.x;
    if (tid < 32) {
        const float mean = stats[tid] * (1.0f / NN);
        const float var  = stats[32 + tid] * (1.0f / NN) - mean * mean;
        const float s = gamma[tid] * rsqrtf(var + EPSV);
        sc[tid] = s;
        sh[tid] = beta[tid] - mean * s;
    }
    __syncthreads();
    const int idx = blockIdx.x * 256 + tid;
    const int c0 = (idx & 3) << 3;
    const __half2 h4[4] = { acc2[idx * 4], acc2[idx * 4 + 1],
                            acc2[idx * 4 + 2], acc2[idx * 4 + 3] };
    float4 o0, o1;
    o0.x = fmaxf(__half2float(h4[0].x) * sc[c0]     + sh[c0],     0.f);
    o0.y = fmaxf(__half2float(h4[0].y) * sc[c0 + 1] + sh[c0 + 1], 0.f);
    o0.z = fmaxf(__half2float(h4[1].x) * sc[c0 + 2] + sh[c0 + 2], 0.f);
    o0.w = fmaxf(__half2float(h4[1].y) * sc[c0 + 3] + sh[c0 + 3], 0.f);
    o1.x = fmaxf(__half2float(h4[2].x) * sc[c0 + 4] + sh[c0 + 4], 0.f);
    o1.y = fmaxf(__half2float(h4[2].y) * sc[c0 + 5] + sh[c0 + 5], 0.f);
    o1.z = fmaxf(__half2float(h4[3].x) * sc[c0 + 6] + sh[c0 + 6], 0.f);
    o1.w = fmaxf(__half2float(h4[3].y) * sc[c0 + 7] + sh[c0 + 7], 0.f);
    ((float4*)out)[idx * 2]     = o0;
    ((float4*)out)[idx * 2 + 1] = o1;
}

// ===========================================================================
// Tier-3 fallback (tiny ws): f32 atomics into d_out.
// ===========================================================================
__global__ __launch_bounds__(256) void scatter_f32_kernel(
    const float* __restrict__ data, const float* __restrict__ weight,
    const int* __restrict__ neigh, float* __restrict__ out)
{
    __shared__ unsigned short wfrag[KK * 2 * 64 * 8];
    const int tid = threadIdx.x;
    const int lane = tid & 63;
    const int wv = tid >> 6;
    const int node_base = blockIdx.x * 128;
    for (int p = tid; p < KK * 1024; p += 256) {
        const int k  = p >> 10;
        const int ci = (p >> 5) & 31;
        const int c  = p & 31;
        const unsigned short v = f2bf(weight[p]);
        const int chalf = c >> 4;
        const int fl = (c & 15) | ((ci >> 3) << 4);
        const int j = ci & 7;
        wfrag[(((k << 1) | chalf) * 64 + fl) * 8 + j] = v;
    }
    const int quad = lane >> 4;
    const int m = lane & 15;
    s16x8 afr[2];
    #pragma unroll
    for (int g = 0; g < 2; ++g) {
        const int node = node_base + wv * 32 + g * 16 + m;
        const float* src = data + node * 32 + quad * 8;
        const float4 v0 = *(const float4*)(src);
        const float4 v1 = *(const float4*)(src + 4);
        s16x8 s;
        s[0] = (short)f2bf(v0.x); s[1] = (short)f2bf(v0.y);
        s[2] = (short)f2bf(v0.z); s[3] = (short)f2bf(v0.w);
        s[4] = (short)f2bf(v1.x); s[5] = (short)f2bf(v1.y);
        s[6] = (short)f2bf(v1.z); s[7] = (short)f2bf(v1.w);
        afr[g] = s;
    }
    __syncthreads();
    const int rq = quad << 2;
    const f32x4 zero = {0.f, 0.f, 0.f, 0.f};
    for (int k = 0; k < KK; ++k) {
        int nj[2][4];
        #pragma unroll
        for (int g = 0; g < 2; ++g)
            #pragma unroll
            for (int r = 0; r < 4; ++r) {
                const int node = node_base + wv * 32 + g * 16 + rq + r;
                nj[g][r] = neigh[node * KK + k];
            }
        #pragma unroll
        for (int ch = 0; ch < 2; ++ch) {
            const s16x8 bs = *(const s16x8*)&wfrag[((((k << 1) | ch)) * 64 + lane) * 8];
            const bf16x8 bfr = __builtin_bit_cast(bf16x8, bs);
            const int c = (ch << 4) | m;
            #pragma unroll
            for (int g = 0; g < 2; ++g) {
                f32x4 a2 = __builtin_amdgcn_mfma_f32_16x16x32_bf16(
                    __builtin_bit_cast(bf16x8, afr[g]), bfr, zero, 0, 0, 0);
                #pragma unroll
                for (int r = 0; r < 4; ++r)
                    __hip_atomic_fetch_add(&out[nj[g][r] * 32 + c], a2[r],
                                           __ATOMIC_RELAXED, __HIP_MEMORY_SCOPE_AGENT);
            }
        }
    }
}

__global__ __launch_bounds__(256) void stats_f32_kernel(
    const float* __restrict__ out, float* __restrict__ stats)
{
    __shared__ float ls[256], ls2[256];
    const int tid = threadIdx.x;
    const int c = tid & 31, rg = tid >> 5;
    float s = 0.f, s2 = 0.f;
    const int row0 = blockIdx.x * 512;
    for (int it = 0; it < 64; ++it) {
        const float v = out[(row0 + it * 8 + rg) * 32 + c];
        s += v; s2 += v * v;
    }
    ls[tid] = s; ls2[tid] = s2;
    __syncthreads();
    if (tid < 32) {
        float S = 0.f, S2 = 0.f;
        #pragma unroll
        for (int r = 0; r < 8; ++r) { S += ls[r * 32 + tid]; S2 += ls2[r * 32 + tid]; }
        atomicAdd(&stats[tid], S);
        atomicAdd(&stats[32 + tid], S2);
    }
}

__global__ __launch_bounds__(256) void bn_relu_f32_kernel(
    float* __restrict__ out, const float* __restrict__ stats,
    const float* __restrict__ gamma, const float* __restrict__ beta)
{
    __shared__ float sc[32], sh[32];
    const int tid = threadIdx.x;
    if (tid < 32) {
        const float mean = stats[tid] * (1.0f / NN);
        const float var  = stats[32 + tid] * (1.0f / NN) - mean * mean;
        const float s = gamma[tid] * rsqrtf(var + EPSV);
        sc[tid] = s;
        sh[tid] = beta[tid] - mean * s;
    }
    __syncthreads();
    const int idx = blockIdx.x * 256 + tid;
    float4 v = ((float4*)out)[idx];
    const int cb = (idx & 7) << 2;
    v.x = fmaxf(v.x * sc[cb]     + sh[cb],     0.f);
    v.y = fmaxf(v.y * sc[cb + 1] + sh[cb + 1], 0.f);
    v.z = fmaxf(v.z * sc[cb + 2] + sh[cb + 2], 0.f);
    v.w = fmaxf(v.w * sc[cb + 3] + sh[cb + 3], 0.f);
    ((float4*)out)[idx] = v;
}

// ===========================================================================
extern "C" void kernel_launch(void* const* d_in, const int* in_sizes, int n_in,
                              void* d_out, int out_size, void* d_ws, size_t ws_size,
                              hipStream_t stream) {
    const float* data   = (const float*)d_in[0];
    const float* weight = (const float*)d_in[1];
    const float* gamma  = (const float*)d_in[2];
    const float* beta   = (const float*)d_in[3];
    const int*   neigh  = (const int*)d_in[4];
    float* out = (float*)d_out;
    char* ws = (char*)d_ws;
    float* stats = (float*)(ws + WS_STATS);

    if (ws_size >= WS_NEEDED) {
        __half2* acc2 = (__half2*)(ws + WS_ACC);
        unsigned short* wperm = (unsigned short*)(ws + WS_WPERM);
        hipMemsetAsync(ws, 0, WS_ACC + (size_t)NN * CC * 2, stream);  // stats+acc

        void* args[] = { (void*)&data, (void*)&weight, (void*)&gamma,
                         (void*)&beta, (void*)&neigh, (void*)&wperm,
                         (void*)&acc2, (void*)&stats, (void*)&out };
        hipError_t rc = hipLaunchCooperativeKernel(
            (const void*)fused_kernel, dim3(512), dim3(512), args, 0, stream);

        if (rc != hipSuccess) {
            // fallback: proven 5-launch path on the same layout
            prep_weights_bf16_kernel<<<(KK * 1024 + 255) / 256, 256, 0, stream>>>(weight, wperm);
            scatter_kernel<<<NN / 128, 256, 0, stream>>>(data, wperm, neigh, acc2);
            stats_kernel<<<NN / 512, 256, 0, stream>>>(acc2, stats);
            bn_relu_kernel<<<(NN * CC / 8) / 256, 256, 0, stream>>>(acc2, out, stats, gamma, beta);
        }
    } else {
        hipMemsetAsync(out, 0, (size_t)NN * CC * sizeof(float), stream);
        hipMemsetAsync(ws + WS_STATS, 0, 64 * sizeof(float), stream);
        scatter_f32_kernel<<<NN / 128, 256, 0, stream>>>(data, weight, neigh, out);
        stats_f32_kernel<<<NN / 512, 256, 0, stream>>>(out, stats);
        bn_relu_f32_kernel<<<(NN * CC / 4) / 256, 256, 0, stream>>>(out, stats, gamma, beta);
    }
}

// Round 6
// 292.619 us; speedup vs baseline: 2.4937x; 1.4579x over previous
//
#include <hip/hip_runtime.h>
#include <hip/hip_bf16.h>
#include <hip/hip_fp16.h>

#define NN 131072
#define KK 27
#define CC 32
#define EPSV 1e-5f
#define NSB 512          // stats_bn grid (NN/256)

// Workspace layout (bytes):
//   [0,512)      f32 stats: [0..31] sum, [32..63] sumsq, [64] ticket (uint)
//   [512,+8.4M)  f16 accumulator (NN x 32 ch)
//   [WS_WPERM]   bf16 permuted weights (55296 B)
#define WS_STATS 0
#define WS_ACC   512
#define WS_WPERM (512 + (size_t)NN * CC * 2)
#define WS_NEEDED (WS_WPERM + 55296)

typedef __bf16 bf16x8 __attribute__((ext_vector_type(8)));
typedef short s16x8 __attribute__((ext_vector_type(8)));
typedef float f32x4 __attribute__((ext_vector_type(4)));

__device__ inline unsigned short f2bf(float f) {
    unsigned int u = __float_as_uint(f);
    u += 0x7FFF + ((u >> 16) & 1);   // round-to-nearest-even
    return (unsigned short)(u >> 16);
}

// ---------------------------------------------------------------------------
// Prep: zero acc2 + stats/ticket, build bf16 wperm. Replaces hipMemsetAsync
// and the old prep dispatch (one launch instead of two).
// wperm layout (proven R0-R5): logical out-channel c computed by MFMA
// ch-half (c&1) at physical column (c>>1); fl = col | ((ci>>3)<<4), j = ci&7.
__global__ __launch_bounds__(256) void prep_zero_kernel(
    const float* __restrict__ weight, unsigned short* __restrict__ wperm,
    uint4* __restrict__ accz, unsigned int* __restrict__ statz)
{
    const int b = blockIdx.x, tid = threadIdx.x;
    if (b < 2048) {                      // 2048*256*16 B = 8.39 MB = acc2
        const uint4 z = {0u, 0u, 0u, 0u};
        accz[b * 256 + tid] = z;
    } else {                             // 108 blocks: 27648 weight elems
        const int p = (b - 2048) * 256 + tid;
        const int k  = p >> 10;
        const int ci = (p >> 5) & 31;
        const int c  = p & 31;
        const unsigned short v = f2bf(weight[p]);
        const int chalf = c & 1;
        const int col   = c >> 1;
        const int fl = col | ((ci >> 3) << 4);
        const int j = ci & 7;
        wperm[(((k << 1) | chalf) * 64 + fl) * 8 + j] = v;
        if (b == 2048 && tid < 128) statz[tid] = 0u;   // stats + ticket (512 B)
    }
}

// ---------------------------------------------------------------------------
// Scatter wave body (R1-proven at 177us; DO NOT change launch config:
// 1024 blocks x 256 thr ~ 11 waves/CU. Measured: 7w->185, 11w->177,
// 16w->~310 us -- the device-atomic fabric LOSES throughput under deeper
// concurrency, so more occupancy is actively harmful here).
__device__ inline void scatter_body(
    const float* __restrict__ data, const unsigned short* __restrict__ wperm,
    const int* __restrict__ neigh, __half2* __restrict__ acc2,
    int node_base, int lane)
{
    const int quad = lane >> 4;
    const int m = lane & 15;
    const int rq = quad << 2;

    s16x8 afr[2];
    #pragma unroll
    for (int g = 0; g < 2; ++g) {
        const int node = node_base + g * 16 + m;
        const float* src = data + node * 32 + quad * 8;
        const float4 v0 = *(const float4*)(src);
        const float4 v1 = *(const float4*)(src + 4);
        s16x8 s;
        s[0] = (short)f2bf(v0.x); s[1] = (short)f2bf(v0.y);
        s[2] = (short)f2bf(v0.z); s[3] = (short)f2bf(v0.w);
        s[4] = (short)f2bf(v1.x); s[5] = (short)f2bf(v1.y);
        s[6] = (short)f2bf(v1.z); s[7] = (short)f2bf(v1.w);
        afr[g] = s;
    }

    const s16x8* wp = (const s16x8*)wperm;
    const f32x4 zero = {0.f, 0.f, 0.f, 0.f};

    int nj0[4], nj1[4];
    #pragma unroll
    for (int r = 0; r < 4; ++r) {
        nj0[r] = neigh[(node_base + rq + r) * KK];
        nj1[r] = neigh[(node_base + 16 + rq + r) * KK];
    }
    s16x8 bs0 = wp[lane];
    s16x8 bs1 = wp[64 + lane];

    for (int k = 0; k < KK; ++k) {
        const int kn = (k < KK - 1) ? k + 1 : k;
        int nn0[4], nn1[4];
        #pragma unroll
        for (int r = 0; r < 4; ++r) {
            nn0[r] = neigh[(node_base + rq + r) * KK + kn];
            nn1[r] = neigh[(node_base + 16 + rq + r) * KK + kn];
        }
        const s16x8 nbs0 = wp[(kn * 2) * 64 + lane];
        const s16x8 nbs1 = wp[(kn * 2 + 1) * 64 + lane];
        {
            const f32x4 d0 = __builtin_amdgcn_mfma_f32_16x16x32_bf16(
                __builtin_bit_cast(bf16x8, afr[0]), __builtin_bit_cast(bf16x8, bs0),
                zero, 0, 0, 0);
            const f32x4 d1 = __builtin_amdgcn_mfma_f32_16x16x32_bf16(
                __builtin_bit_cast(bf16x8, afr[0]), __builtin_bit_cast(bf16x8, bs1),
                zero, 0, 0, 0);
            #pragma unroll
            for (int r = 0; r < 4; ++r) {
                __half2 v;
                v.x = __float2half(d0[r]);
                v.y = __float2half(d1[r]);
                unsafeAtomicAdd(&acc2[nj0[r] * 16 + m], v);
            }
        }
        {
            const f32x4 d0 = __builtin_amdgcn_mfma_f32_16x16x32_bf16(
                __builtin_bit_cast(bf16x8, afr[1]), __builtin_bit_cast(bf16x8, bs0),
                zero, 0, 0, 0);
            const f32x4 d1 = __builtin_amdgcn_mfma_f32_16x16x32_bf16(
                __builtin_bit_cast(bf16x8, afr[1]), __builtin_bit_cast(bf16x8, bs1),
                zero, 0, 0, 0);
            #pragma unroll
            for (int r = 0; r < 4; ++r) {
                __half2 v;
                v.x = __float2half(d0[r]);
                v.y = __float2half(d1[r]);
                unsafeAtomicAdd(&acc2[nj1[r] * 16 + m], v);
            }
        }
        bs0 = nbs0; bs1 = nbs1;
        #pragma unroll
        for (int r = 0; r < 4; ++r) { nj0[r] = nn0[r]; nj1[r] = nn1[r]; }
    }
}

__global__ __launch_bounds__(256) void scatter_kernel(
    const float* __restrict__ data, const unsigned short* __restrict__ wperm,
    const int* __restrict__ neigh, __half2* __restrict__ acc2)
{
    const int tid = threadIdx.x;
    scatter_body(data, wperm, neigh, acc2,
                 blockIdx.x * 128 + (tid >> 6) * 32, tid & 63);
}

// ---------------------------------------------------------------------------
// Fused stats+bn with a device-atomic ticket barrier (no cooperative launch).
// Grid 512 x 256 thr, __launch_bounds__(256,2): 512 blocks <= 2 blocks/CU
// floor x 256 CUs -> all co-resident, spin is deadlock-free.
// Each block: stage its 256 rows in LDS once -> partial sum/sumsq ->
// atomicAdd global stats -> ticket release -> spin acquire -> read final
// stats (agent-scope atomic loads bypass L1) -> BN+ReLU from LDS.
__global__ __launch_bounds__(256, 2) void stats_bn_kernel(
    const __half2* __restrict__ acc2, float* __restrict__ out,
    float* __restrict__ stats,
    const float* __restrict__ gamma, const float* __restrict__ beta)
{
    __shared__ __half2 rowbuf[256][16];          // 16 KB: this block's rows
    __shared__ float ls[16][32], ls2[16][32];    // 4 KB
    __shared__ float sc[32], sh[32];
    const int tid = threadIdx.x;
    const int bb = blockIdx.x;

    // stage 256 rows (16 KB) coalesced
    {
        const uint4* src = (const uint4*)(acc2 + (size_t)bb * 256 * 16);
        uint4* dst = (uint4*)&rowbuf[0][0];
        #pragma unroll
        for (int it = 0; it < 4; ++it)
            dst[tid + it * 256] = src[tid + it * 256];
    }
    __syncthreads();

    // partial per-channel stats
    const int c2 = tid & 15, rg = tid >> 4;
    {
        float sx = 0.f, sy = 0.f, qx = 0.f, qy = 0.f;
        #pragma unroll
        for (int it = 0; it < 16; ++it) {
            const __half2 h = rowbuf[it * 16 + rg][c2];
            const float vx = __half2float(h.x), vy = __half2float(h.y);
            sx += vx; sy += vy; qx += vx * vx; qy += vy * vy;
        }
        ls[rg][2 * c2] = sx;  ls[rg][2 * c2 + 1] = sy;
        ls2[rg][2 * c2] = qx; ls2[rg][2 * c2 + 1] = qy;
    }
    __syncthreads();
    if (tid < 32) {
        float S = 0.f, S2 = 0.f;
        #pragma unroll
        for (int g = 0; g < 16; ++g) { S += ls[g][tid]; S2 += ls2[g][tid]; }
        atomicAdd(&stats[tid], S);
        atomicAdd(&stats[32 + tid], S2);
    }
    // ticket barrier (wave 0 issued the stats atomics; release orders them)
    if (tid == 0) {
        unsigned int* ticket = (unsigned int*)(stats + 64);
        __hip_atomic_fetch_add(ticket, 1u, __ATOMIC_RELEASE,
                               __HIP_MEMORY_SCOPE_AGENT);
        while (__hip_atomic_load(ticket, __ATOMIC_ACQUIRE,
                                 __HIP_MEMORY_SCOPE_AGENT) < NSB)
            __builtin_amdgcn_s_sleep(8);
    }
    __syncthreads();
    if (tid < 32) {
        const float S  = __hip_atomic_load(&stats[tid], __ATOMIC_RELAXED,
                                           __HIP_MEMORY_SCOPE_AGENT);
        const float S2 = __hip_atomic_load(&stats[32 + tid], __ATOMIC_RELAXED,
                                           __HIP_MEMORY_SCOPE_AGENT);
        const float mean = S * (1.0f / NN);
        const float var  = S2 * (1.0f / NN) - mean * mean;
        const float s = gamma[tid] * rsqrtf(var + EPSV);
        sc[tid] = s;
        sh[tid] = beta[tid] - mean * s;
    }
    __syncthreads();

    // BN + ReLU from LDS; float2 stores, wave covers 4 consecutive rows
    {
        const float s0 = sc[2 * c2], s1 = sc[2 * c2 + 1];
        const float h0 = sh[2 * c2], h1 = sh[2 * c2 + 1];
        #pragma unroll
        for (int it = 0; it < 16; ++it) {
            const int row = it * 16 + rg;
            const __half2 h = rowbuf[row][c2];
            float2 v;
            v.x = fmaxf(__half2float(h.x) * s0 + h0, 0.f);
            v.y = fmaxf(__half2float(h.y) * s1 + h1, 0.f);
            *(float2*)(out + ((size_t)(bb * 256 + row)) * 32 + 2 * c2) = v;
        }
    }
}

// ===========================================================================
// Tier-3 fallback (tiny ws): f32 atomics into d_out.
// ===========================================================================
__global__ __launch_bounds__(256) void scatter_f32_kernel(
    const float* __restrict__ data, const float* __restrict__ weight,
    const int* __restrict__ neigh, float* __restrict__ out)
{
    __shared__ unsigned short wfrag[KK * 2 * 64 * 8];
    const int tid = threadIdx.x;
    const int lane = tid & 63;
    const int wv = tid >> 6;
    const int node_base = blockIdx.x * 128;
    for (int p = tid; p < KK * 1024; p += 256) {
        const int k  = p >> 10;
        const int ci = (p >> 5) & 31;
        const int c  = p & 31;
        const unsigned short v = f2bf(weight[p]);
        const int chalf = c >> 4;
        const int fl = (c & 15) | ((ci >> 3) << 4);
        const int j = ci & 7;
        wfrag[(((k << 1) | chalf) * 64 + fl) * 8 + j] = v;
    }
    const int quad = lane >> 4;
    const int m = lane & 15;
    s16x8 afr[2];
    #pragma unroll
    for (int g = 0; g < 2; ++g) {
        const int node = node_base + wv * 32 + g * 16 + m;
        const float* src = data + node * 32 + quad * 8;
        const float4 v0 = *(const float4*)(src);
        const float4 v1 = *(const float4*)(src + 4);
        s16x8 s;
        s[0] = (short)f2bf(v0.x); s[1] = (short)f2bf(v0.y);
        s[2] = (short)f2bf(v0.z); s[3] = (short)f2bf(v0.w);
        s[4] = (short)f2bf(v1.x); s[5] = (short)f2bf(v1.y);
        s[6] = (short)f2bf(v1.z); s[7] = (short)f2bf(v1.w);
        afr[g] = s;
    }
    __syncthreads();
    const int rq = quad << 2;
    const f32x4 zero = {0.f, 0.f, 0.f, 0.f};
    for (int k = 0; k < KK; ++k) {
        int nj[2][4];
        #pragma unroll
        for (int g = 0; g < 2; ++g)
            #pragma unroll
            for (int r = 0; r < 4; ++r) {
                const int node = node_base + wv * 32 + g * 16 + rq + r;
                nj[g][r] = neigh[node * KK + k];
            }
        #pragma unroll
        for (int ch = 0; ch < 2; ++ch) {
            const s16x8 bs = *(const s16x8*)&wfrag[((((k << 1) | ch)) * 64 + lane) * 8];
            const bf16x8 bfr = __builtin_bit_cast(bf16x8, bs);
            const int c = (ch << 4) | m;
            #pragma unroll
            for (int g = 0; g < 2; ++g) {
                f32x4 a2 = __builtin_amdgcn_mfma_f32_16x16x32_bf16(
                    __builtin_bit_cast(bf16x8, afr[g]), bfr, zero, 0, 0, 0);
                #pragma unroll
                for (int r = 0; r < 4; ++r)
                    __hip_atomic_fetch_add(&out[nj[g][r] * 32 + c], a2[r],
                                           __ATOMIC_RELAXED, __HIP_MEMORY_SCOPE_AGENT);
            }
        }
    }
}

__global__ __launch_bounds__(256) void stats_f32_kernel(
    const float* __restrict__ out, float* __restrict__ stats)
{
    __shared__ float ls[256], ls2[256];
    const int tid = threadIdx.x;
    const int c = tid & 31, rg = tid >> 5;
    float s = 0.f, s2 = 0.f;
    const int row0 = blockIdx.x * 512;
    for (int it = 0; it < 64; ++it) {
        const float v = out[(row0 + it * 8 + rg) * 32 + c];
        s += v; s2 += v * v;
    }
    ls[tid] = s; ls2[tid] = s2;
    __syncthreads();
    if (tid < 32) {
        float S = 0.f, S2 = 0.f;
        #pragma unroll
        for (int r = 0; r < 8; ++r) { S += ls[r * 32 + tid]; S2 += ls2[r * 32 + tid]; }
        atomicAdd(&stats[tid], S);
        atomicAdd(&stats[32 + tid], S2);
    }
}

__global__ __launch_bounds__(256) void bn_relu_f32_kernel(
    float* __restrict__ out, const float* __restrict__ stats,
    const float* __restrict__ gamma, const float* __restrict__ beta)
{
    __shared__ float sc[32], sh[32];
    const int tid = threadIdx.x;
    if (tid < 32) {
        const float mean = stats[tid] * (1.0f / NN);
        const float var  = stats[32 + tid] * (1.0f / NN) - mean * mean;
        const float s = gamma[tid] * rsqrtf(var + EPSV);
        sc[tid] = s;
        sh[tid] = beta[tid] - mean * s;
    }
    __syncthreads();
    const int idx = blockIdx.x * 256 + tid;
    float4 v = ((float4*)out)[idx];
    const int cb = (idx & 7) << 2;
    v.x = fmaxf(v.x * sc[cb]     + sh[cb],     0.f);
    v.y = fmaxf(v.y * sc[cb + 1] + sh[cb + 1], 0.f);
    v.z = fmaxf(v.z * sc[cb + 2] + sh[cb + 2], 0.f);
    v.w = fmaxf(v.w * sc[cb + 3] + sh[cb + 3], 0.f);
    ((float4*)out)[idx] = v;
}

// ===========================================================================
extern "C" void kernel_launch(void* const* d_in, const int* in_sizes, int n_in,
                              void* d_out, int out_size, void* d_ws, size_t ws_size,
                              hipStream_t stream) {
    const float* data   = (const float*)d_in[0];
    const float* weight = (const float*)d_in[1];
    const float* gamma  = (const float*)d_in[2];
    const float* beta   = (const float*)d_in[3];
    const int*   neigh  = (const int*)d_in[4];
    float* out = (float*)d_out;
    char* ws = (char*)d_ws;
    float* stats = (float*)(ws + WS_STATS);

    if (ws_size >= WS_NEEDED) {
        __half2* acc2 = (__half2*)(ws + WS_ACC);
        unsigned short* wperm = (unsigned short*)(ws + WS_WPERM);
        prep_zero_kernel<<<2156, 256, 0, stream>>>(
            weight, wperm, (uint4*)(ws + WS_ACC), (unsigned int*)stats);
        scatter_kernel<<<NN / 128, 256, 0, stream>>>(data, wperm, neigh, acc2);
        stats_bn_kernel<<<NSB, 256, 0, stream>>>(acc2, out, stats, gamma, beta);
    } else {
        hipMemsetAsync(out, 0, (size_t)NN * CC * sizeof(float), stream);
        hipMemsetAsync(ws + WS_STATS, 0, 64 * sizeof(float), stream);
        scatter_f32_kernel<<<NN / 128, 256, 0, stream>>>(data, weight, neigh, out);
        stats_f32_kernel<<<NN / 512, 256, 0, stream>>>(out, stats);
        bn_relu_f32_kernel<<<(NN * CC / 4) / 256, 256, 0, stream>>>(out, stats, gamma, beta);
    }
}

// Round 7
// 285.602 us; speedup vs baseline: 2.5550x; 1.0246x over previous
//
#include <hip/hip_runtime.h>
#include <hip/hip_bf16.h>
#include <hip/hip_fp16.h>

#define NN 131072
#define KK 27
#define CC 32
#define EPSV 1e-5f
#define NSB 512          // stats_bn grid (NN/256)

// Workspace layout (bytes):
//   [0,512)      f32 stats: [0..31] sum, [32..63] sumsq, [64] ticket (uint)
//   [512,+8.4M)  f16 accumulator (NN x 32 ch)
//   [WS_WPERM]   bf16 permuted weights (55296 B)
#define WS_STATS 0
#define WS_ACC   512
#define WS_WPERM (512 + (size_t)NN * CC * 2)
#define WS_NEEDED (WS_WPERM + 55296)

typedef __bf16 bf16x8 __attribute__((ext_vector_type(8)));
typedef short s16x8 __attribute__((ext_vector_type(8)));
typedef float f32x4 __attribute__((ext_vector_type(4)));

__device__ inline unsigned short f2bf(float f) {
    unsigned int u = __float_as_uint(f);
    u += 0x7FFF + ((u >> 16) & 1);   // round-to-nearest-even
    return (unsigned short)(u >> 16);
}

// ---------------------------------------------------------------------------
// Prep: zero acc2 + stats/ticket, build bf16 wperm. Replaces hipMemsetAsync
// and the old prep dispatch (one launch instead of two).
// wperm layout (proven R0-R6): logical out-channel c computed by MFMA
// ch-half (c&1) at physical column (c>>1); fl = col | ((ci>>3)<<4), j = ci&7.
__global__ __launch_bounds__(256) void prep_zero_kernel(
    const float* __restrict__ weight, unsigned short* __restrict__ wperm,
    uint4* __restrict__ accz, unsigned int* __restrict__ statz)
{
    const int b = blockIdx.x, tid = threadIdx.x;
    if (b < 2048) {                      // 2048*256*16 B = 8.39 MB = acc2
        const uint4 z = {0u, 0u, 0u, 0u};
        accz[b * 256 + tid] = z;
    } else {                             // 108 blocks: 27648 weight elems
        const int p = (b - 2048) * 256 + tid;
        const int k  = p >> 10;
        const int ci = (p >> 5) & 31;
        const int c  = p & 31;
        const unsigned short v = f2bf(weight[p]);
        const int chalf = c & 1;
        const int col   = c >> 1;
        const int fl = col | ((ci >> 3) << 4);
        const int j = ci & 7;
        wperm[(((k << 1) | chalf) * 64 + fl) * 8 + j] = v;
        if (b == 2048 && tid < 128) statz[tid] = 0u;   // stats + ticket (512 B)
    }
}

// ---------------------------------------------------------------------------
// Scatter wave body (R1-proven at 177us; DO NOT change launch config:
// 1024 blocks x 256 thr ~ 11 waves/CU. Measured: 7w->185, 11w->177,
// 16w->~310 us -- the device-atomic fabric LOSES throughput under deeper
// concurrency, so more occupancy is actively harmful here).
__device__ inline void scatter_body(
    const float* __restrict__ data, const unsigned short* __restrict__ wperm,
    const int* __restrict__ neigh, __half2* __restrict__ acc2,
    int node_base, int lane)
{
    const int quad = lane >> 4;
    const int m = lane & 15;
    const int rq = quad << 2;

    s16x8 afr[2];
    #pragma unroll
    for (int g = 0; g < 2; ++g) {
        const int node = node_base + g * 16 + m;
        const float* src = data + node * 32 + quad * 8;
        const float4 v0 = *(const float4*)(src);
        const float4 v1 = *(const float4*)(src + 4);
        s16x8 s;
        s[0] = (short)f2bf(v0.x); s[1] = (short)f2bf(v0.y);
        s[2] = (short)f2bf(v0.z); s[3] = (short)f2bf(v0.w);
        s[4] = (short)f2bf(v1.x); s[5] = (short)f2bf(v1.y);
        s[6] = (short)f2bf(v1.z); s[7] = (short)f2bf(v1.w);
        afr[g] = s;
    }

    const s16x8* wp = (const s16x8*)wperm;
    const f32x4 zero = {0.f, 0.f, 0.f, 0.f};

    int nj0[4], nj1[4];
    #pragma unroll
    for (int r = 0; r < 4; ++r) {
        nj0[r] = neigh[(node_base + rq + r) * KK];
        nj1[r] = neigh[(node_base + 16 + rq + r) * KK];
    }
    s16x8 bs0 = wp[lane];
    s16x8 bs1 = wp[64 + lane];

    for (int k = 0; k < KK; ++k) {
        const int kn = (k < KK - 1) ? k + 1 : k;
        int nn0[4], nn1[4];
        #pragma unroll
        for (int r = 0; r < 4; ++r) {
            nn0[r] = neigh[(node_base + rq + r) * KK + kn];
            nn1[r] = neigh[(node_base + 16 + rq + r) * KK + kn];
        }
        const s16x8 nbs0 = wp[(kn * 2) * 64 + lane];
        const s16x8 nbs1 = wp[(kn * 2 + 1) * 64 + lane];
        {
            const f32x4 d0 = __builtin_amdgcn_mfma_f32_16x16x32_bf16(
                __builtin_bit_cast(bf16x8, afr[0]), __builtin_bit_cast(bf16x8, bs0),
                zero, 0, 0, 0);
            const f32x4 d1 = __builtin_amdgcn_mfma_f32_16x16x32_bf16(
                __builtin_bit_cast(bf16x8, afr[0]), __builtin_bit_cast(bf16x8, bs1),
                zero, 0, 0, 0);
            #pragma unroll
            for (int r = 0; r < 4; ++r) {
                __half2 v;
                v.x = __float2half(d0[r]);
                v.y = __float2half(d1[r]);
                unsafeAtomicAdd(&acc2[nj0[r] * 16 + m], v);
            }
        }
        {
            const f32x4 d0 = __builtin_amdgcn_mfma_f32_16x16x32_bf16(
                __builtin_bit_cast(bf16x8, afr[1]), __builtin_bit_cast(bf16x8, bs0),
                zero, 0, 0, 0);
            const f32x4 d1 = __builtin_amdgcn_mfma_f32_16x16x32_bf16(
                __builtin_bit_cast(bf16x8, afr[1]), __builtin_bit_cast(bf16x8, bs1),
                zero, 0, 0, 0);
            #pragma unroll
            for (int r = 0; r < 4; ++r) {
                __half2 v;
                v.x = __float2half(d0[r]);
                v.y = __float2half(d1[r]);
                unsafeAtomicAdd(&acc2[nj1[r] * 16 + m], v);
            }
        }
        bs0 = nbs0; bs1 = nbs1;
        #pragma unroll
        for (int r = 0; r < 4; ++r) { nj0[r] = nn0[r]; nj1[r] = nn1[r]; }
    }
}

__global__ __launch_bounds__(256) void scatter_kernel(
    const float* __restrict__ data, const unsigned short* __restrict__ wperm,
    const int* __restrict__ neigh, __half2* __restrict__ acc2)
{
    const int tid = threadIdx.x;
    scatter_body(data, wperm, neigh, acc2,
                 blockIdx.x * 128 + (tid >> 6) * 32, tid & 63);
}

// ---------------------------------------------------------------------------
// Fused stats+bn with a device-atomic ticket barrier (no cooperative launch).
// Grid 512 x 256 thr, __launch_bounds__(256,2): 512 blocks <= 2 blocks/CU
// floor x 256 CUs -> all co-resident, spin is deadlock-free.
//
// Barrier protocol (R7 fix): arrive with ONE acq_rel fetch_add (single L2
// writeback publishing this block's stats atomics), spin on RELAXED atomic
// loads (coherence-point reads, NO per-poll cache maintenance -- R6's
// acquire-per-poll emitted an L2 invalidate every ~0.2us from 512 spinners,
// ~70us of thrash), then ONE acquire load after exit.
__global__ __launch_bounds__(256, 2) void stats_bn_kernel(
    const __half2* __restrict__ acc2, float* __restrict__ out,
    float* __restrict__ stats,
    const float* __restrict__ gamma, const float* __restrict__ beta)
{
    __shared__ __half2 rowbuf[256][16];          // 16 KB: this block's rows
    __shared__ float ls[16][32], ls2[16][32];    // 4 KB
    __shared__ float sc[32], sh[32];
    const int tid = threadIdx.x;
    const int bb = blockIdx.x;

    // stage 256 rows (16 KB) coalesced
    {
        const uint4* src = (const uint4*)(acc2 + (size_t)bb * 256 * 16);
        uint4* dst = (uint4*)&rowbuf[0][0];
        #pragma unroll
        for (int it = 0; it < 4; ++it)
            dst[tid + it * 256] = src[tid + it * 256];
    }
    __syncthreads();

    // partial per-channel stats
    const int c2 = tid & 15, rg = tid >> 4;
    {
        float sx = 0.f, sy = 0.f, qx = 0.f, qy = 0.f;
        #pragma unroll
        for (int it = 0; it < 16; ++it) {
            const __half2 h = rowbuf[it * 16 + rg][c2];
            const float vx = __half2float(h.x), vy = __half2float(h.y);
            sx += vx; sy += vy; qx += vx * vx; qy += vy * vy;
        }
        ls[rg][2 * c2] = sx;  ls[rg][2 * c2 + 1] = sy;
        ls2[rg][2 * c2] = qx; ls2[rg][2 * c2 + 1] = qy;
    }
    __syncthreads();
    if (tid < 32) {
        float S = 0.f, S2 = 0.f;
        #pragma unroll
        for (int g = 0; g < 16; ++g) { S += ls[g][tid]; S2 += ls2[g][tid]; }
        atomicAdd(&stats[tid], S);
        atomicAdd(&stats[32 + tid], S2);
    }
    // ticket barrier: acq_rel arrive, RELAXED polls, single acquire on exit
    if (tid == 0) {
        unsigned int* ticket = (unsigned int*)(stats + 64);
        __hip_atomic_fetch_add(ticket, 1u, __ATOMIC_ACQ_REL,
                               __HIP_MEMORY_SCOPE_AGENT);
        while (__hip_atomic_load(ticket, __ATOMIC_RELAXED,
                                 __HIP_MEMORY_SCOPE_AGENT) < NSB)
            __builtin_amdgcn_s_sleep(16);
        (void)__hip_atomic_load(ticket, __ATOMIC_ACQUIRE,
                                __HIP_MEMORY_SCOPE_AGENT);
    }
    __syncthreads();
    if (tid < 32) {
        const float S  = __hip_atomic_load(&stats[tid], __ATOMIC_RELAXED,
                                           __HIP_MEMORY_SCOPE_AGENT);
        const float S2 = __hip_atomic_load(&stats[32 + tid], __ATOMIC_RELAXED,
                                           __HIP_MEMORY_SCOPE_AGENT);
        const float mean = S * (1.0f / NN);
        const float var  = S2 * (1.0f / NN) - mean * mean;
        const float s = gamma[tid] * rsqrtf(var + EPSV);
        sc[tid] = s;
        sh[tid] = beta[tid] - mean * s;
    }
    __syncthreads();

    // BN + ReLU from LDS; float2 stores, 16 lanes cover 128B per row
    {
        const float s0 = sc[2 * c2], s1 = sc[2 * c2 + 1];
        const float h0 = sh[2 * c2], h1 = sh[2 * c2 + 1];
        #pragma unroll
        for (int it = 0; it < 16; ++it) {
            const int row = it * 16 + rg;
            const __half2 h = rowbuf[row][c2];
            float2 v;
            v.x = fmaxf(__half2float(h.x) * s0 + h0, 0.f);
            v.y = fmaxf(__half2float(h.y) * s1 + h1, 0.f);
            *(float2*)(out + ((size_t)(bb * 256 + row)) * 32 + 2 * c2) = v;
        }
    }
}

// ===========================================================================
// Tier-3 fallback (tiny ws): f32 atomics into d_out.
// ===========================================================================
__global__ __launch_bounds__(256) void scatter_f32_kernel(
    const float* __restrict__ data, const float* __restrict__ weight,
    const int* __restrict__ neigh, float* __restrict__ out)
{
    __shared__ unsigned short wfrag[KK * 2 * 64 * 8];
    const int tid = threadIdx.x;
    const int lane = tid & 63;
    const int wv = tid >> 6;
    const int node_base = blockIdx.x * 128;
    for (int p = tid; p < KK * 1024; p += 256) {
        const int k  = p >> 10;
        const int ci = (p >> 5) & 31;
        const int c  = p & 31;
        const unsigned short v = f2bf(weight[p]);
        const int chalf = c >> 4;
        const int fl = (c & 15) | ((ci >> 3) << 4);
        const int j = ci & 7;
        wfrag[(((k << 1) | chalf) * 64 + fl) * 8 + j] = v;
    }
    const int quad = lane >> 4;
    const int m = lane & 15;
    s16x8 afr[2];
    #pragma unroll
    for (int g = 0; g < 2; ++g) {
        const int node = node_base + wv * 32 + g * 16 + m;
        const float* src = data + node * 32 + quad * 8;
        const float4 v0 = *(const float4*)(src);
        const float4 v1 = *(const float4*)(src + 4);
        s16x8 s;
        s[0] = (short)f2bf(v0.x); s[1] = (short)f2bf(v0.y);
        s[2] = (short)f2bf(v0.z); s[3] = (short)f2bf(v0.w);
        s[4] = (short)f2bf(v1.x); s[5] = (short)f2bf(v1.y);
        s[6] = (short)f2bf(v1.z); s[7] = (short)f2bf(v1.w);
        afr[g] = s;
    }
    __syncthreads();
    const int rq = quad << 2;
    const f32x4 zero = {0.f, 0.f, 0.f, 0.f};
    for (int k = 0; k < KK; ++k) {
        int nj[2][4];
        #pragma unroll
        for (int g = 0; g < 2; ++g)
            #pragma unroll
            for (int r = 0; r < 4; ++r) {
                const int node = node_base + wv * 32 + g * 16 + rq + r;
                nj[g][r] = neigh[node * KK + k];
            }
        #pragma unroll
        for (int ch = 0; ch < 2; ++ch) {
            const s16x8 bs = *(const s16x8*)&wfrag[((((k << 1) | ch)) * 64 + lane) * 8];
            const bf16x8 bfr = __builtin_bit_cast(bf16x8, bs);
            const int c = (ch << 4) | m;
            #pragma unroll
            for (int g = 0; g < 2; ++g) {
                f32x4 a2 = __builtin_amdgcn_mfma_f32_16x16x32_bf16(
                    __builtin_bit_cast(bf16x8, afr[g]), bfr, zero, 0, 0, 0);
                #pragma unroll
                for (int r = 0; r < 4; ++r)
                    __hip_atomic_fetch_add(&out[nj[g][r] * 32 + c], a2[r],
                                           __ATOMIC_RELAXED, __HIP_MEMORY_SCOPE_AGENT);
            }
        }
    }
}

__global__ __launch_bounds__(256) void stats_f32_kernel(
    const float* __restrict__ out, float* __restrict__ stats)
{
    __shared__ float ls[256], ls2[256];
    const int tid = threadIdx.x;
    const int c = tid & 31, rg = tid >> 5;
    float s = 0.f, s2 = 0.f;
    const int row0 = blockIdx.x * 512;
    for (int it = 0; it < 64; ++it) {
        const float v = out[(row0 + it * 8 + rg) * 32 + c];
        s += v; s2 += v * v;
    }
    ls[tid] = s; ls2[tid] = s2;
    __syncthreads();
    if (tid < 32) {
        float S = 0.f, S2 = 0.f;
        #pragma unroll
        for (int r = 0; r < 8; ++r) { S += ls[r * 32 + tid]; S2 += ls2[r * 32 + tid]; }
        atomicAdd(&stats[tid], S);
        atomicAdd(&stats[32 + tid], S2);
    }
}

__global__ __launch_bounds__(256) void bn_relu_f32_kernel(
    float* __restrict__ out, const float* __restrict__ stats,
    const float* __restrict__ gamma, const float* __restrict__ beta)
{
    __shared__ float sc[32], sh[32];
    const int tid = threadIdx.x;
    if (tid < 32) {
        const float mean = stats[tid] * (1.0f / NN);
        const float var  = stats[32 + tid] * (1.0f / NN) - mean * mean;
        const float s = gamma[tid] * rsqrtf(var + EPSV);
        sc[tid] = s;
        sh[tid] = beta[tid] - mean * s;
    }
    __syncthreads();
    const int idx = blockIdx.x * 256 + tid;
    float4 v = ((float4*)out)[idx];
    const int cb = (idx & 7) << 2;
    v.x = fmaxf(v.x * sc[cb]     + sh[cb],     0.f);
    v.y = fmaxf(v.y * sc[cb + 1] + sh[cb + 1], 0.f);
    v.z = fmaxf(v.z * sc[cb + 2] + sh[cb + 2], 0.f);
    v.w = fmaxf(v.w * sc[cb + 3] + sh[cb + 3], 0.f);
    ((float4*)out)[idx] = v;
}

// ===========================================================================
extern "C" void kernel_launch(void* const* d_in, const int* in_sizes, int n_in,
                              void* d_out, int out_size, void* d_ws, size_t ws_size,
                              hipStream_t stream) {
    const float* data   = (const float*)d_in[0];
    const float* weight = (const float*)d_in[1];
    const float* gamma  = (const float*)d_in[2];
    const float* beta   = (const float*)d_in[3];
    const int*   neigh  = (const int*)d_in[4];
    float* out = (float*)d_out;
    char* ws = (char*)d_ws;
    float* stats = (float*)(ws + WS_STATS);

    if (ws_size >= WS_NEEDED) {
        __half2* acc2 = (__half2*)(ws + WS_ACC);
        unsigned short* wperm = (unsigned short*)(ws + WS_WPERM);
        prep_zero_kernel<<<2156, 256, 0, stream>>>(
            weight, wperm, (uint4*)(ws + WS_ACC), (unsigned int*)stats);
        scatter_kernel<<<NN / 128, 256, 0, stream>>>(data, wperm, neigh, acc2);
        stats_bn_kernel<<<NSB, 256, 0, stream>>>(acc2, out, stats, gamma, beta);
    } else {
        hipMemsetAsync(out, 0, (size_t)NN * CC * sizeof(float), stream);
        hipMemsetAsync(ws + WS_STATS, 0, 64 * sizeof(float), stream);
        scatter_f32_kernel<<<NN / 128, 256, 0, stream>>>(data, weight, neigh, out);
        stats_f32_kernel<<<NN / 512, 256, 0, stream>>>(out, stats);
        bn_relu_f32_kernel<<<(NN * CC / 4) / 256, 256, 0, stream>>>(out, stats, gamma, beta);
    }
}

// Round 8
// 272.487 us; speedup vs baseline: 2.6779x; 1.0481x over previous
//
#include <hip/hip_runtime.h>
#include <hip/hip_bf16.h>
#include <hip/hip_fp16.h>

#define NN 131072
#define KK 27
#define CC 32
#define EPSV 1e-5f

// Workspace layout (bytes) -- R1-proven configuration (271.4 us):
//   [0,256)        f32 stats (sum, sumsq per channel)
//   [256,+55296)   bf16 permuted weights
//   [65536,+8.4M)  f16 accumulator (NN x 16 half2)
#define WS_STATS 0
#define WS_WPERM 256
#define WS_ACC   65536
#define WS_NEEDED ((size_t)WS_ACC + (size_t)NN * CC * 2)

typedef __bf16 bf16x8 __attribute__((ext_vector_type(8)));
typedef short s16x8 __attribute__((ext_vector_type(8)));
typedef float f32x4 __attribute__((ext_vector_type(4)));

__device__ inline unsigned short f2bf(float f) {
    unsigned int u = __float_as_uint(f);
    u += 0x7FFF + ((u >> 16) & 1);   // round-to-nearest-even
    return (unsigned short)(u >> 16);
}

// ---------------------------------------------------------------------------
// Pre-permute f32 weight [K][CIN][COUT] into bf16 MFMA B-fragment layout.
// Logical out-channel c computed by MFMA ch-half (c&1) at physical column
// (c>>1); fragment element (fl, j): fl = col | ((ci>>3)<<4), j = ci&7.
__global__ __launch_bounds__(256) void prep_weights_kernel(
    const float* __restrict__ weight, unsigned short* __restrict__ wperm)
{
    const int p = blockIdx.x * 256 + threadIdx.x;
    if (p >= KK * 1024) return;
    const int k  = p >> 10;
    const int ci = (p >> 5) & 31;
    const int c  = p & 31;
    const unsigned short v = f2bf(weight[p]);
    const int chalf = c & 1;           // parity -> which MFMA
    const int col   = c >> 1;          // physical column 0..15
    const int fl = col | ((ci >> 3) << 4);
    const int j = ci & 7;
    wperm[(((k << 1) | chalf) * 64 + fl) * 8 + j] = v;
}

// ---------------------------------------------------------------------------
// Scatter (R1-proven at 177us). DO NOT change launch config: 1024 blocks x
// 256 thr. Concurrency scan measured 7w/CU->185, 11w/CU->177, 16w/CU->~310us
// -- the device-scope atomic fabric LOSES throughput under deeper
// concurrency. 56.6M 4B pk-f16 atomics at the measured ~320 G ops/s fabric
// rate = the 177us floor; verified invariant across 4 kernel structures
// (R0 LDS-staged, R1 prefetched, R4 gather, R5 cooperative).
//
// Structure: tap k+1's neigh indices and B-fragments are prefetched into
// registers BEFORE tap k's atomics are issued; vmcnt retires FIFO, so the
// wait for the prefetched loads never drains the atomics -- the wave never
// blocks on atomic completion.
__global__ __launch_bounds__(256) void scatter_kernel(
    const float* __restrict__ data, const unsigned short* __restrict__ wperm,
    const int* __restrict__ neigh, __half2* __restrict__ acc2)
{
    const int tid = threadIdx.x;
    const int lane = tid & 63;
    const int wv = tid >> 6;
    const int node_base = blockIdx.x * 128 + wv * 32;
    const int quad = lane >> 4;
    const int m = lane & 15;
    const int rq = quad << 2;

    s16x8 afr[2];
    #pragma unroll
    for (int g = 0; g < 2; ++g) {
        const int node = node_base + g * 16 + m;
        const float* src = data + node * 32 + quad * 8;
        const float4 v0 = *(const float4*)(src);
        const float4 v1 = *(const float4*)(src + 4);
        s16x8 s;
        s[0] = (short)f2bf(v0.x); s[1] = (short)f2bf(v0.y);
        s[2] = (short)f2bf(v0.z); s[3] = (short)f2bf(v0.w);
        s[4] = (short)f2bf(v1.x); s[5] = (short)f2bf(v1.y);
        s[6] = (short)f2bf(v1.z); s[7] = (short)f2bf(v1.w);
        afr[g] = s;
    }

    const s16x8* wp = (const s16x8*)wperm;
    const f32x4 zero = {0.f, 0.f, 0.f, 0.f};

    int nj0[4], nj1[4];
    #pragma unroll
    for (int r = 0; r < 4; ++r) {
        nj0[r] = neigh[(node_base + rq + r) * KK];
        nj1[r] = neigh[(node_base + 16 + rq + r) * KK];
    }
    s16x8 bs0 = wp[lane];
    s16x8 bs1 = wp[64 + lane];

    for (int k = 0; k < KK; ++k) {
        const int kn = (k < KK - 1) ? k + 1 : k;
        int nn0[4], nn1[4];
        #pragma unroll
        for (int r = 0; r < 4; ++r) {
            nn0[r] = neigh[(node_base + rq + r) * KK + kn];
            nn1[r] = neigh[(node_base + 16 + rq + r) * KK + kn];
        }
        const s16x8 nbs0 = wp[(kn * 2) * 64 + lane];
        const s16x8 nbs1 = wp[(kn * 2 + 1) * 64 + lane];
        {
            const f32x4 d0 = __builtin_amdgcn_mfma_f32_16x16x32_bf16(
                __builtin_bit_cast(bf16x8, afr[0]), __builtin_bit_cast(bf16x8, bs0),
                zero, 0, 0, 0);
            const f32x4 d1 = __builtin_amdgcn_mfma_f32_16x16x32_bf16(
                __builtin_bit_cast(bf16x8, afr[0]), __builtin_bit_cast(bf16x8, bs1),
                zero, 0, 0, 0);
            #pragma unroll
            for (int r = 0; r < 4; ++r) {
                __half2 v;
                v.x = __float2half(d0[r]);   // logical channel 2m
                v.y = __float2half(d1[r]);   // logical channel 2m+1
                unsafeAtomicAdd(&acc2[nj0[r] * 16 + m], v);
            }
        }
        {
            const f32x4 d0 = __builtin_amdgcn_mfma_f32_16x16x32_bf16(
                __builtin_bit_cast(bf16x8, afr[1]), __builtin_bit_cast(bf16x8, bs0),
                zero, 0, 0, 0);
            const f32x4 d1 = __builtin_amdgcn_mfma_f32_16x16x32_bf16(
                __builtin_bit_cast(bf16x8, afr[1]), __builtin_bit_cast(bf16x8, bs1),
                zero, 0, 0, 0);
            #pragma unroll
            for (int r = 0; r < 4; ++r) {
                __half2 v;
                v.x = __float2half(d0[r]);
                v.y = __float2half(d1[r]);
                unsafeAtomicAdd(&acc2[nj1[r] * 16 + m], v);
            }
        }
        bs0 = nbs0; bs1 = nbs1;
        #pragma unroll
        for (int r = 0; r < 4; ++r) { nj0[r] = nn0[r]; nj1[r] = nn1[r]; }
    }
}

// ---------------------------------------------------------------------------
// Per-channel sum/sumsq over the f16 accumulator. Block covers 512 rows.
__global__ __launch_bounds__(256) void stats_kernel(
    const __half2* __restrict__ acc2, float* __restrict__ stats)
{
    __shared__ float ls[16][33], ls2[16][33];   // [rowgroup][channel] (+pad)
    const int tid = threadIdx.x;
    const int c2 = tid & 15, rg = tid >> 4;     // 16 half2-cols x 16 rowgroups
    float sx = 0.f, sy = 0.f, s2x = 0.f, s2y = 0.f;
    const int row0 = blockIdx.x * 512;
    for (int it = 0; it < 32; ++it) {
        const __half2 h = acc2[(row0 + it * 16 + rg) * 16 + c2];
        const float vx = __half2float(h.x), vy = __half2float(h.y);
        sx += vx; sy += vy; s2x += vx * vx; s2y += vy * vy;
    }
    ls[rg][2 * c2] = sx;  ls[rg][2 * c2 + 1] = sy;
    ls2[rg][2 * c2] = s2x; ls2[rg][2 * c2 + 1] = s2y;
    __syncthreads();
    if (tid < 32) {
        float S = 0.f, S2 = 0.f;
        #pragma unroll
        for (int g = 0; g < 16; ++g) { S += ls[g][tid]; S2 += ls2[g][tid]; }
        atomicAdd(&stats[tid], S);
        atomicAdd(&stats[32 + tid], S2);
    }
}

// ---------------------------------------------------------------------------
// y = gamma*(x-mean)*rsqrt(var+eps)+beta, relu. Reads f16 accum, writes f32.
__global__ __launch_bounds__(256) void bn_relu_kernel(
    const __half2* __restrict__ acc2, float* __restrict__ out,
    const float* __restrict__ stats,
    const float* __restrict__ gamma, const float* __restrict__ beta)
{
    __shared__ float sc[32], sh[32];
    const int tid = threadIdx.x;
    if (tid < 32) {
        const float mean = stats[tid] * (1.0f / NN);
        const float var  = stats[32 + tid] * (1.0f / NN) - mean * mean;
        const float s = gamma[tid] * rsqrtf(var + EPSV);
        sc[tid] = s;
        sh[tid] = beta[tid] - mean * s;
    }
    __syncthreads();
    const int idx = blockIdx.x * 256 + tid;      // idx over groups of 4 half2
    const int c0 = (idx & 3) << 3;               // channel base within row
    const __half2 h4[4] = { acc2[idx * 4], acc2[idx * 4 + 1],
                            acc2[idx * 4 + 2], acc2[idx * 4 + 3] };
    float4 o0, o1;
    o0.x = fmaxf(__half2float(h4[0].x) * sc[c0]     + sh[c0],     0.f);
    o0.y = fmaxf(__half2float(h4[0].y) * sc[c0 + 1] + sh[c0 + 1], 0.f);
    o0.z = fmaxf(__half2float(h4[1].x) * sc[c0 + 2] + sh[c0 + 2], 0.f);
    o0.w = fmaxf(__half2float(h4[1].y) * sc[c0 + 3] + sh[c0 + 3], 0.f);
    o1.x = fmaxf(__half2float(h4[2].x) * sc[c0 + 4] + sh[c0 + 4], 0.f);
    o1.y = fmaxf(__half2float(h4[2].y) * sc[c0 + 5] + sh[c0 + 5], 0.f);
    o1.z = fmaxf(__half2float(h4[3].x) * sc[c0 + 6] + sh[c0 + 6], 0.f);
    o1.w = fmaxf(__half2float(h4[3].y) * sc[c0 + 7] + sh[c0 + 7], 0.f);
    ((float4*)out)[idx * 2]     = o0;
    ((float4*)out)[idx * 2 + 1] = o1;
}

// ===========================================================================
// Fallback (small ws): f32 atomics into d_out.
// ===========================================================================
__global__ __launch_bounds__(256) void scatter_f32_kernel(
    const float* __restrict__ data, const float* __restrict__ weight,
    const int* __restrict__ neigh, float* __restrict__ out)
{
    __shared__ unsigned short wfrag[KK * 2 * 64 * 8];
    const int tid = threadIdx.x;
    const int lane = tid & 63;
    const int wv = tid >> 6;
    const int node_base = blockIdx.x * 128;
    for (int p = tid; p < KK * 1024; p += 256) {
        const int k  = p >> 10;
        const int ci = (p >> 5) & 31;
        const int c  = p & 31;
        const unsigned short v = f2bf(weight[p]);
        const int chalf = c >> 4;
        const int fl = (c & 15) | ((ci >> 3) << 4);
        const int j = ci & 7;
        wfrag[(((k << 1) | chalf) * 64 + fl) * 8 + j] = v;
    }
    const int quad = lane >> 4;
    const int m = lane & 15;
    s16x8 afr[2];
    #pragma unroll
    for (int g = 0; g < 2; ++g) {
        const int node = node_base + wv * 32 + g * 16 + m;
        const float* src = data + node * 32 + quad * 8;
        const float4 v0 = *(const float4*)(src);
        const float4 v1 = *(const float4*)(src + 4);
        s16x8 s;
        s[0] = (short)f2bf(v0.x); s[1] = (short)f2bf(v0.y);
        s[2] = (short)f2bf(v0.z); s[3] = (short)f2bf(v0.w);
        s[4] = (short)f2bf(v1.x); s[5] = (short)f2bf(v1.y);
        s[6] = (short)f2bf(v1.z); s[7] = (short)f2bf(v1.w);
        afr[g] = s;
    }
    __syncthreads();
    const int rq = quad << 2;
    const f32x4 zero = {0.f, 0.f, 0.f, 0.f};
    for (int k = 0; k < KK; ++k) {
        int nj[2][4];
        #pragma unroll
        for (int g = 0; g < 2; ++g)
            #pragma unroll
            for (int r = 0; r < 4; ++r) {
                const int node = node_base + wv * 32 + g * 16 + rq + r;
                nj[g][r] = neigh[node * KK + k];
            }
        #pragma unroll
        for (int ch = 0; ch < 2; ++ch) {
            const s16x8 bs = *(const s16x8*)&wfrag[((((k << 1) | ch)) * 64 + lane) * 8];
            const bf16x8 bfr = __builtin_bit_cast(bf16x8, bs);
            const int c = (ch << 4) | m;
            #pragma unroll
            for (int g = 0; g < 2; ++g) {
                f32x4 a2 = __builtin_amdgcn_mfma_f32_16x16x32_bf16(
                    __builtin_bit_cast(bf16x8, afr[g]), bfr, zero, 0, 0, 0);
                #pragma unroll
                for (int r = 0; r < 4; ++r)
                    __hip_atomic_fetch_add(&out[nj[g][r] * 32 + c], a2[r],
                                           __ATOMIC_RELAXED, __HIP_MEMORY_SCOPE_AGENT);
            }
        }
    }
}

__global__ __launch_bounds__(256) void stats_f32_kernel(
    const float* __restrict__ out, float* __restrict__ stats)
{
    __shared__ float ls[256], ls2[256];
    const int tid = threadIdx.x;
    const int c = tid & 31, rg = tid >> 5;
    float s = 0.f, s2 = 0.f;
    const int row0 = blockIdx.x * 512;
    for (int it = 0; it < 64; ++it) {
        const float v = out[(row0 + it * 8 + rg) * 32 + c];
        s += v; s2 += v * v;
    }
    ls[tid] = s; ls2[tid] = s2;
    __syncthreads();
    if (tid < 32) {
        float S = 0.f, S2 = 0.f;
        #pragma unroll
        for (int r = 0; r < 8; ++r) { S += ls[r * 32 + tid]; S2 += ls2[r * 32 + tid]; }
        atomicAdd(&stats[tid], S);
        atomicAdd(&stats[32 + tid], S2);
    }
}

__global__ __launch_bounds__(256) void bn_relu_f32_kernel(
    float* __restrict__ out, const float* __restrict__ stats,
    const float* __restrict__ gamma, const float* __restrict__ beta)
{
    __shared__ float sc[32], sh[32];
    const int tid = threadIdx.x;
    if (tid < 32) {
        const float mean = stats[tid] * (1.0f / NN);
        const float var  = stats[32 + tid] * (1.0f / NN) - mean * mean;
        const float s = gamma[tid] * rsqrtf(var + EPSV);
        sc[tid] = s;
        sh[tid] = beta[tid] - mean * s;
    }
    __syncthreads();
    const int idx = blockIdx.x * 256 + tid;
    float4 v = ((float4*)out)[idx];
    const int cb = (idx & 7) << 2;
    v.x = fmaxf(v.x * sc[cb]     + sh[cb],     0.f);
    v.y = fmaxf(v.y * sc[cb + 1] + sh[cb + 1], 0.f);
    v.z = fmaxf(v.z * sc[cb + 2] + sh[cb + 2], 0.f);
    v.w = fmaxf(v.w * sc[cb + 3] + sh[cb + 3], 0.f);
    ((float4*)out)[idx] = v;
}

// ===========================================================================
extern "C" void kernel_launch(void* const* d_in, const int* in_sizes, int n_in,
                              void* d_out, int out_size, void* d_ws, size_t ws_size,
                              hipStream_t stream) {
    const float* data   = (const float*)d_in[0];
    const float* weight = (const float*)d_in[1];
    const float* gamma  = (const float*)d_in[2];
    const float* beta   = (const float*)d_in[3];
    const int*   neigh  = (const int*)d_in[4];
    float* out = (float*)d_out;
    char* ws = (char*)d_ws;
    float* stats = (float*)(ws + WS_STATS);

    if (ws_size >= WS_NEEDED) {
        __half2* acc2 = (__half2*)(ws + WS_ACC);
        unsigned short* wperm = (unsigned short*)(ws + WS_WPERM);
        hipMemsetAsync(ws + WS_STATS, 0, 256, stream);
        hipMemsetAsync(ws + WS_ACC, 0, (size_t)NN * CC * 2, stream);
        prep_weights_kernel<<<(KK * 1024 + 255) / 256, 256, 0, stream>>>(weight, wperm);
        scatter_kernel<<<NN / 128, 256, 0, stream>>>(data, wperm, neigh, acc2);
        stats_kernel<<<NN / 512, 256, 0, stream>>>(acc2, stats);
        bn_relu_kernel<<<(NN * CC / 8) / 256, 256, 0, stream>>>(acc2, out, stats, gamma, beta);
    } else {
        hipMemsetAsync(out, 0, (size_t)NN * CC * sizeof(float), stream);
        hipMemsetAsync(ws + WS_STATS, 0, 64 * sizeof(float), stream);
        scatter_f32_kernel<<<NN / 128, 256, 0, stream>>>(data, weight, neigh, out);
        stats_f32_kernel<<<NN / 512, 256, 0, stream>>>(out, stats);
        bn_relu_f32_kernel<<<(NN * CC / 4) / 256, 256, 0, stream>>>(out, stats, gamma, beta);
    }
}